// Round 2
// baseline (7686.824 us; speedup 1.0000x reference)
//
#include <hip/hip_runtime.h>

// Problem constants (fixed by the reference)
constexpr int kN = 50000;
constexpr int kE = 300000;
constexpr int kDIN = 963;
constexpr int kH = 256;
constexpr int kDOUT = 3;
constexpr int kNBLK = 6;
constexpr long kNH = (long)kN * kH;   // 12,800,000

// ---------------------------------------------------------------------------
// Tiled fp32 GEMM: C = A(MxK) @ B(KxN) [+ bias], row-major, BN|N, 64x64x16 tile
// ---------------------------------------------------------------------------
__global__ __launch_bounds__(256) void gemm_bias_kernel(
    const float* __restrict__ A, const float* __restrict__ B,
    const float* __restrict__ bias, float* __restrict__ C,
    int M, int K, int N)
{
    __shared__ float As[16][68];   // [kk][row], padded to avoid bank conflicts
    __shared__ float Bs[16][64];   // [kk][col]

    const int tid = threadIdx.x;
    const int tx = tid & 15;       // 0..15 -> 4 output cols each
    const int ty = tid >> 4;       // 0..15 -> 4 output rows each
    const int row0 = blockIdx.y * 64;
    const int col0 = blockIdx.x * 64;

    // A-load mapping: thread covers 4 consecutive k of one row
    const int ar = tid >> 2;            // 0..63 row within tile
    const int ak = (tid & 3) << 2;      // 0,4,8,12 k base
    // B-load mapping: one float4 per thread
    const int bc = tx << 2;             // col within tile
    const int bk = ty;                  // k within tile

    float acc[4][4] = {{0.f,0.f,0.f,0.f},{0.f,0.f,0.f,0.f},
                       {0.f,0.f,0.f,0.f},{0.f,0.f,0.f,0.f}};

    for (int k0 = 0; k0 < K; k0 += 16) {
        const int grow = row0 + ar;
        const long abase = (long)grow * K + k0 + ak;
#pragma unroll
        for (int i = 0; i < 4; ++i) {
            int gk = k0 + ak + i;
            As[ak + i][ar] = (grow < M && gk < K) ? A[abase + i] : 0.f;
        }
        {
            int gk = k0 + bk;
            float4 v = make_float4(0.f, 0.f, 0.f, 0.f);
            if (gk < K) v = *(const float4*)(&B[(long)gk * N + col0 + bc]);
            Bs[bk][bc + 0] = v.x; Bs[bk][bc + 1] = v.y;
            Bs[bk][bc + 2] = v.z; Bs[bk][bc + 3] = v.w;
        }
        __syncthreads();
#pragma unroll
        for (int kk = 0; kk < 16; ++kk) {
            float a[4], b[4];
#pragma unroll
            for (int i = 0; i < 4; ++i) a[i] = As[kk][(ty << 2) + i];
#pragma unroll
            for (int j = 0; j < 4; ++j) b[j] = Bs[kk][(tx << 2) + j];
#pragma unroll
            for (int i = 0; i < 4; ++i)
#pragma unroll
                for (int j = 0; j < 4; ++j)
                    acc[i][j] = fmaf(a[i], b[j], acc[i][j]);
        }
        __syncthreads();
    }

    float b0 = 0.f, b1 = 0.f, b2v = 0.f, b3 = 0.f;
    if (bias) {
        b0 = bias[col0 + bc + 0]; b1 = bias[col0 + bc + 1];
        b2v = bias[col0 + bc + 2]; b3 = bias[col0 + bc + 3];
    }
#pragma unroll
    for (int i = 0; i < 4; ++i) {
        int r = row0 + (ty << 2) + i;
        if (r < M) {
            float4 v;
            v.x = acc[i][0] + b0; v.y = acc[i][1] + b1;
            v.z = acc[i][2] + b2v; v.w = acc[i][3] + b3;
            *(float4*)(&C[(long)r * N + col0 + bc]) = v;
        }
    }
}

// ---------------------------------------------------------------------------
// Edge scatter: out[dst[e], :] += ew[e] * sup[src[e], :]   (H = 256 columns)
// one block (256 threads) per edge
// ---------------------------------------------------------------------------
__global__ __launch_bounds__(256) void scatter_h_kernel(
    const float* __restrict__ sup, const int* __restrict__ src,
    const int* __restrict__ dst, const float* __restrict__ ew,
    float* __restrict__ out)
{
    const int e = blockIdx.x;
    const int c = threadIdx.x;
    const int s = src[e];
    const int d = dst[e];
    const float w = ew[e];
    atomicAdd(&out[(long)d * kH + c], w * sup[(long)s * kH + c]);
}

// ---------------------------------------------------------------------------
// Elementwise
// ---------------------------------------------------------------------------
__global__ __launch_bounds__(256) void relu_kernel(float4* __restrict__ x, int n4)
{
    int i = blockIdx.x * 256 + threadIdx.x;
    if (i < n4) {
        float4 v = x[i];
        v.x = fmaxf(v.x, 0.f); v.y = fmaxf(v.y, 0.f);
        v.z = fmaxf(v.z, 0.f); v.w = fmaxf(v.w, 0.f);
        x[i] = v;
    }
}

__global__ __launch_bounds__(256) void add_halve_kernel(
    float4* __restrict__ h, const float4* __restrict__ t, int n4)
{
    int i = blockIdx.x * 256 + threadIdx.x;
    if (i < n4) {
        float4 a = h[i];
        float4 b = t[i];
        a.x = (a.x + b.x) * 0.5f; a.y = (a.y + b.y) * 0.5f;
        a.z = (a.z + b.z) * 0.5f; a.w = (a.w + b.w) * 0.5f;
        h[i] = a;
    }
}

// ---------------------------------------------------------------------------
// Final layer: sup2 = h @ W2 (Nx3), x_out = h @ Wl2 + b2 ; one wave per row
// ---------------------------------------------------------------------------
__global__ __launch_bounds__(64) void final_layer_kernel(
    const float* __restrict__ h, const float* __restrict__ W2,
    const float* __restrict__ Wl2, const float* __restrict__ b2,
    float* __restrict__ sup2, float* __restrict__ x_out)
{
    const int row = blockIdx.x;
    const int lane = threadIdx.x;   // 0..63
    const float* hr = h + (long)row * kH;
    float accW[3] = {0.f, 0.f, 0.f};
    float accL[3] = {0.f, 0.f, 0.f};
#pragma unroll
    for (int kb = 0; kb < kH / 64; ++kb) {
        int k = kb * 64 + lane;
        float v = hr[k];
#pragma unroll
        for (int c = 0; c < 3; ++c) {
            accW[c] = fmaf(v, W2[k * 3 + c], accW[c]);
            accL[c] = fmaf(v, Wl2[k * 3 + c], accL[c]);
        }
    }
#pragma unroll
    for (int off = 32; off > 0; off >>= 1) {
#pragma unroll
        for (int c = 0; c < 3; ++c) {
            accW[c] += __shfl_down(accW[c], off);
            accL[c] += __shfl_down(accL[c], off);
        }
    }
    if (lane == 0) {
#pragma unroll
        for (int c = 0; c < 3; ++c) {
            sup2[row * 3 + c] = accW[c];
            x_out[row * 3 + c] = accL[c] + b2[c];
        }
    }
}

__global__ __launch_bounds__(256) void scatter3_kernel(
    const float* __restrict__ sup2, const int* __restrict__ src,
    const int* __restrict__ dst, const float* __restrict__ ew,
    float* __restrict__ x_out)
{
    int e = blockIdx.x * 256 + threadIdx.x;
    if (e >= kE) return;
    int s = src[e];
    int d = dst[e];
    float w = ew[e];
#pragma unroll
    for (int c = 0; c < 3; ++c)
        atomicAdd(&x_out[(long)d * 3 + c], w * sup2[(long)s * 3 + c]);
}

// ---------------------------------------------------------------------------
// Host-side launch
// ---------------------------------------------------------------------------
extern "C" void kernel_launch(void* const* d_in, const int* in_sizes, int n_in,
                              void* d_out, int out_size, void* d_ws, size_t ws_size,
                              hipStream_t stream)
{
    const float* x   = (const float*)d_in[0];
    const int*   src = (const int*)d_in[1];
    const int*   dst = (const int*)d_in[2];
    const float* ew  = (const float*)d_in[3];
    const float* W1  = (const float*)d_in[4];
    const float* Wl1 = (const float*)d_in[5];
    const float* b1  = (const float*)d_in[6];
    const float* blkW  = (const float*)d_in[7];
    const float* blkWl = (const float*)d_in[8];
    const float* blkb  = (const float*)d_in[9];
    const float* W2  = (const float*)d_in[10];
    const float* Wl2 = (const float*)d_in[11];
    const float* b2  = (const float*)d_in[12];

    float* out   = (float*)d_out;
    float* x_out = out;                       // N*3
    float* h     = out + (long)kN * kDOUT;    // N*H — IS the x_hidden output

    float* wsf  = (float*)d_ws;
    float* sup  = wsf;                        // N*H
    float* t1   = wsf + kNH;                  // N*H
    float* t2   = wsf + 2 * kNH;              // N*H
    float* sup2 = wsf + 3 * kNH;              // N*3

    const int mtiles = (kN + 63) / 64;        // 782
    const dim3 g256(kH / 64, mtiles);         // 4 x 782 (N-cols = 256)
    const int n4 = (int)(kNH / 4);            // 3.2M
    const int eg = (n4 + 255) / 256;

    // ---- Layer 1: h = relu(gconv(x, W1, Wl1, b1)), K = 963
    gemm_bias_kernel<<<g256, 256, 0, stream>>>(x, W1, nullptr, sup, kN, kDIN, kH);
    gemm_bias_kernel<<<g256, 256, 0, stream>>>(x, Wl1, b1, h, kN, kDIN, kH);
    scatter_h_kernel<<<kE, 256, 0, stream>>>(sup, src, dst, ew, h);
    relu_kernel<<<eg, 256, 0, stream>>>((float4*)h, n4);

    // ---- Residual blocks
    for (int b = 0; b < kNBLK; ++b) {
        const float* W0  = blkW  + ((long)b * 2 + 0) * kH * kH;
        const float* Wl0 = blkWl + ((long)b * 2 + 0) * kH * kH;
        const float* b0  = blkb  + ((long)b * 2 + 0) * kH;
        const float* Wc1  = blkW  + ((long)b * 2 + 1) * kH * kH;
        const float* Wlc1 = blkWl + ((long)b * 2 + 1) * kH * kH;
        const float* bc1  = blkb  + ((long)b * 2 + 1) * kH;

        // conv0: t1 = relu(gconv(h, ...))
        gemm_bias_kernel<<<g256, 256, 0, stream>>>(h, W0, nullptr, sup, kN, kH, kH);
        gemm_bias_kernel<<<g256, 256, 0, stream>>>(h, Wl0, b0, t1, kN, kH, kH);
        scatter_h_kernel<<<kE, 256, 0, stream>>>(sup, src, dst, ew, t1);
        relu_kernel<<<eg, 256, 0, stream>>>((float4*)t1, n4);

        // conv1: t2 = relu(gconv(t1, ...))
        gemm_bias_kernel<<<g256, 256, 0, stream>>>(t1, Wc1, nullptr, sup, kN, kH, kH);
        gemm_bias_kernel<<<g256, 256, 0, stream>>>(t1, Wlc1, bc1, t2, kN, kH, kH);
        scatter_h_kernel<<<kE, 256, 0, stream>>>(sup, src, dst, ew, t2);
        relu_kernel<<<eg, 256, 0, stream>>>((float4*)t2, n4);

        // residual: h = (h + t2) * 0.5
        add_halve_kernel<<<eg, 256, 0, stream>>>((float4*)h, (const float4*)t2, n4);
    }

    // ---- Final layer: x_out = gconv(h, W2, Wl2, b2), DOUT = 3
    final_layer_kernel<<<kN, 64, 0, stream>>>(h, W2, Wl2, b2, sup2, x_out);
    scatter3_kernel<<<(kE + 255) / 256, 256, 0, stream>>>(sup2, src, dst, ew, x_out);
}

// Round 3
// 2271.077 us; speedup vs baseline: 3.3847x; 3.3847x over previous
//
#include <hip/hip_runtime.h>

typedef __attribute__((ext_vector_type(8))) short short8;
typedef __attribute__((ext_vector_type(4))) float f32x4;

constexpr int kN = 50000;
constexpr int kE = 300000;
constexpr int kDIN = 963;
constexpr int kH = 256;
constexpr int kNBLK = 6;

__device__ inline unsigned short f2bf(float f) {
    unsigned u = __float_as_uint(f);
    u = u + 0x7FFFu + ((u >> 16) & 1u);   // RTNE
    return (unsigned short)(u >> 16);
}
__device__ inline float bf2f(unsigned short s) {
    return __uint_as_float(((unsigned)s) << 16);
}

__device__ inline void gload_lds16(const void* g, void* l) {
    __builtin_amdgcn_global_load_lds(
        (const __attribute__((address_space(1))) void*)g,
        (__attribute__((address_space(3))) void*)l, 16, 0, 0);
}

// ---------------------------------------------------------------------------
// Dual GEMM: [supb | tpre] = A(MxK) @ Bt^T, Bt is [512][Kpad] bf16 (cols of
// W|Wl stored as rows). Output cols 0..255 -> supb (bf16), 256..511 -> tpre
// (fp32, +bias). 128x128 tile, 4 waves 2x2, mfma_f32_16x16x32_bf16 with
// swapped operands so lane&15 = output row (coalesced stores).
// LDS: A[128][64] bf16 + B[128][64] bf16, XOR-swizzled (chunk16 ^= row&7),
// filled by global_load_lds with pre-swizzled global source (m173 pattern).
// ---------------------------------------------------------------------------
template<bool ACVT>
__global__ __launch_bounds__(256) void gemm_dual(
    const void* __restrict__ Av, const unsigned short* __restrict__ Bt,
    const float* __restrict__ bias,
    unsigned short* __restrict__ supb, float* __restrict__ tpre,
    int M, int Kpad, int Kvalid, int Astride)
{
    __shared__ __align__(16) char smem[32768];
    char* As = smem;             // 128 rows x 64 k (bf16, swizzled)
    char* Bs = smem + 16384;     // 128 cols x 64 k

    const int tid = threadIdx.x;
    const int wid = tid >> 6;
    const int lane = tid & 63;
    const int wr = wid >> 1, wc = wid & 1;
    const int r0 = blockIdx.y * 128;
    const int c0 = blockIdx.x * 128;

    f32x4 acc[4][4];
#pragma unroll
    for (int i = 0; i < 4; ++i)
#pragma unroll
        for (int j = 0; j < 4; ++j) acc[i][j] = f32x4{0.f, 0.f, 0.f, 0.f};

    const int srow_base = wid * 32;   // wave covers 32 rows of each tile
    const int l_row = lane >> 3;      // 0..7
    const int l_c   = lane & 7;       // 16B chunk

    for (int k0 = 0; k0 < Kpad; k0 += 64) {
        // ---- stage B (weights, bf16, gload_lds direct)
#pragma unroll
        for (int p = 0; p < 4; ++p) {
            int row = srow_base + p * 8 + l_row;
            int csw = l_c ^ (row & 7);
            const unsigned short* g = Bt + (long)(c0 + row) * Kpad + k0 + csw * 8;
            gload_lds16(g, Bs + (srow_base + p * 8) * 128);
        }
        if (!ACVT) {
            const unsigned short* A = (const unsigned short*)Av;
#pragma unroll
            for (int p = 0; p < 4; ++p) {
                int row = srow_base + p * 8 + l_row;
                int grow = r0 + row; if (grow >= M) grow = M - 1;
                int csw = l_c ^ (row & 7);
                const unsigned short* g = A + (long)grow * Astride + k0 + csw * 8;
                gload_lds16(g, As + (srow_base + p * 8) * 128);
            }
        } else {
            // reg-stage fp32 A -> bf16 LDS (layer 1: x, K=963, Kpad=1024)
            const int row = tid >> 1;
            const int khalf = tid & 1;
            int grow = r0 + row; if (grow >= M) grow = M - 1;
            const float* ar = (const float*)Av + (long)grow * Astride;
#pragma unroll
            for (int j = 0; j < 4; ++j) {
                int k16 = khalf * 4 + j;
                short8 v;
#pragma unroll
                for (int ii = 0; ii < 8; ++ii) {
                    int k = k0 + k16 * 8 + ii;
                    float f = (k < Kvalid) ? ar[k] : 0.f;
                    v[ii] = (short)f2bf(f);
                }
                *(short8*)(As + row * 128 + ((k16 ^ (row & 7)) << 4)) = v;
            }
        }
        __syncthreads();

        // ---- compute: 2 x (8 ds_read_b128 + 16 MFMA)
#pragma unroll
        for (int kk = 0; kk < 2; ++kk) {
            short8 af[4], bfr[4];
            const int kg = kk * 4 + (lane >> 4);   // logical 16B chunk 0..7
#pragma unroll
            for (int nr = 0; nr < 4; ++nr) {
                int row = wr * 64 + nr * 16 + (lane & 15);
                af[nr] = *(const short8*)(As + row * 128 + ((kg ^ (row & 7)) << 4));
            }
#pragma unroll
            for (int mc = 0; mc < 4; ++mc) {
                int row = wc * 64 + mc * 16 + (lane & 15);
                bfr[mc] = *(const short8*)(Bs + row * 128 + ((kg ^ (row & 7)) << 4));
            }
#pragma unroll
            for (int mc = 0; mc < 4; ++mc)
#pragma unroll
                for (int nr = 0; nr < 4; ++nr)
                    acc[mc][nr] = __builtin_amdgcn_mfma_f32_16x16x32_bf16(
                        bfr[mc], af[nr], acc[mc][nr], 0, 0, 0);
        }
        __syncthreads();
    }

    // ---- epilogue: lane holds out_row = .. + (lane&15), 4 consecutive cols
    const bool isSup = (c0 < 256);
#pragma unroll
    for (int mc = 0; mc < 4; ++mc) {
        const int gcol = c0 + wc * 64 + mc * 16 + ((lane >> 4) << 2);
#pragma unroll
        for (int nr = 0; nr < 4; ++nr) {
            const int r = r0 + wr * 64 + nr * 16 + (lane & 15);
            if (r >= M) continue;
            f32x4 v = acc[mc][nr];
            if (isSup) {
                uint2 pk;
                pk.x = (unsigned)f2bf(v[0]) | ((unsigned)f2bf(v[1]) << 16);
                pk.y = (unsigned)f2bf(v[2]) | ((unsigned)f2bf(v[3]) << 16);
                *(uint2*)(supb + (long)r * 256 + gcol) = pk;
            } else {
                const int tc = gcol - 256;
                const f32x4 b4 = *(const f32x4*)(bias + tc);
                v += b4;
                *(f32x4*)(tpre + (long)r * 256 + tc) = v;
            }
        }
    }
}

// ---------------------------------------------------------------------------
// CSR-gather aggregation, fused epilogue. One wave per node, lane owns 4 cols.
// MODE 0: tact_bf = bf16(relu(tpre + agg))
// MODE 1: h = (h + relu(tpre + agg)) * 0.5 ; hbf = bf16(h)
// MODE 2: h = relu(tpre + agg)             ; hbf = bf16(h)
// ---------------------------------------------------------------------------
template<int MODE>
__global__ __launch_bounds__(256) void agg_kernel(
    const unsigned short* __restrict__ supb, const float* __restrict__ tpre,
    const int* __restrict__ rowptr, const int* __restrict__ e_src,
    const float* __restrict__ e_w,
    float* __restrict__ h, unsigned short* __restrict__ obf)
{
    const int wid = threadIdx.x >> 6, lane = threadIdx.x & 63;
    const long node = (long)blockIdx.x * 4 + wid;
    if (node >= kN) return;
    const int c0 = lane << 2;

    f32x4 a = *(const f32x4*)(tpre + node * 256 + c0);
    int b = rowptr[node];
    const int e = rowptr[node + 1];
    for (; b < e; ++b) {
        const int s = e_src[b];
        const float w = e_w[b];
        ushort4 sv = *(const ushort4*)(supb + (long)s * 256 + c0);
        a[0] += w * bf2f(sv.x); a[1] += w * bf2f(sv.y);
        a[2] += w * bf2f(sv.z); a[3] += w * bf2f(sv.w);
    }
    a[0] = fmaxf(a[0], 0.f); a[1] = fmaxf(a[1], 0.f);
    a[2] = fmaxf(a[2], 0.f); a[3] = fmaxf(a[3], 0.f);

    f32x4 r = a;
    if (MODE == 1) {
        f32x4 hv = *(const f32x4*)(h + node * 256 + c0);
        r = (hv + a) * 0.5f;
    }
    if (MODE == 1 || MODE == 2)
        *(f32x4*)(h + node * 256 + c0) = r;

    uint2 pk;
    pk.x = (unsigned)f2bf(r[0]) | ((unsigned)f2bf(r[1]) << 16);
    pk.y = (unsigned)f2bf(r[2]) | ((unsigned)f2bf(r[3]) << 16);
    *(uint2*)(obf + node * 256 + c0) = pk;
}

// ---------------------------------------------------------------------------
// Weight conversion
// ---------------------------------------------------------------------------
__global__ __launch_bounds__(256) void cvt_w1_kernel(
    const float* __restrict__ W1, const float* __restrict__ Wl1,
    unsigned short* __restrict__ out)
{
    int idx = blockIdx.x * 256 + threadIdx.x;       // 512*1024
    if (idx >= 512 * 1024) return;
    int c = idx >> 10, k = idx & 1023;
    float v = 0.f;
    if (k < kDIN) v = (c < 256) ? W1[(long)k * 256 + c] : Wl1[(long)k * 256 + (c - 256)];
    out[idx] = f2bf(v);
}

__global__ __launch_bounds__(256) void cvt_blk_kernel(
    const float* __restrict__ blkW, const float* __restrict__ blkWl,
    unsigned short* __restrict__ out)
{
    int idx = blockIdx.x * 256 + threadIdx.x;       // 12*512*256
    if (idx >= 12 * 512 * 256) return;
    int l = idx >> 17;
    int rem = idx & 131071;
    int c = rem >> 8, k = rem & 255;
    float v = (c < 256) ? blkW[((long)l * 256 + k) * 256 + c]
                        : blkWl[((long)l * 256 + k) * 256 + (c - 256)];
    out[idx] = f2bf(v);
}

// ---------------------------------------------------------------------------
// CSR build: histogram -> hierarchical exclusive scan -> fill
// ---------------------------------------------------------------------------
__global__ __launch_bounds__(256) void hist_kernel(const int* __restrict__ dst,
                                                   int* __restrict__ counts)
{
    int e = blockIdx.x * 256 + threadIdx.x;
    if (e < kE) atomicAdd(&counts[dst[e]], 1);
}

__global__ __launch_bounds__(1024) void scan1_kernel(
    const int* __restrict__ counts, int* __restrict__ rowptr, int* __restrict__ bsum)
{
    __shared__ int s[1024];
    const int tid = threadIdx.x;
    const int g = blockIdx.x * 1024 + tid;
    const int v = (g < kN) ? counts[g] : 0;
    s[tid] = v; __syncthreads();
    for (int off = 1; off < 1024; off <<= 1) {
        int t = (tid >= off) ? s[tid - off] : 0;
        __syncthreads();
        s[tid] += t;
        __syncthreads();
    }
    if (g < kN) rowptr[g] = s[tid] - v;   // block-local exclusive
    if (tid == 1023) bsum[blockIdx.x] = s[1023];
}

__global__ __launch_bounds__(64) void scan2_kernel(int* __restrict__ bsum, int nb)
{
    __shared__ int s[64];
    const int tid = threadIdx.x;
    const int v = (tid < nb) ? bsum[tid] : 0;
    s[tid] = v; __syncthreads();
    for (int off = 1; off < 64; off <<= 1) {
        int t = (tid >= off) ? s[tid - off] : 0;
        __syncthreads();
        s[tid] += t;
        __syncthreads();
    }
    if (tid < nb) bsum[tid] = s[tid] - v;  // exclusive
}

__global__ __launch_bounds__(256) void scan3_kernel(
    int* __restrict__ rowptr, const int* __restrict__ bsum, int* __restrict__ cursor)
{
    int g = blockIdx.x * 256 + threadIdx.x;
    if (g < kN) {
        int r = rowptr[g] + bsum[g >> 10];
        rowptr[g] = r;
        cursor[g] = r;
    }
    if (g == 0) rowptr[kN] = kE;
}

__global__ __launch_bounds__(256) void fill_kernel(
    const int* __restrict__ src, const int* __restrict__ dst,
    const float* __restrict__ ew, int* __restrict__ cursor,
    int* __restrict__ e_src, float* __restrict__ e_w)
{
    int e = blockIdx.x * 256 + threadIdx.x;
    if (e >= kE) return;
    int d = dst[e];
    int pos = atomicAdd(&cursor[d], 1);
    e_src[pos] = src[e];
    e_w[pos] = ew[e];
}

// ---------------------------------------------------------------------------
// Final layer (fp32, DOUT=3): one wave per row
// ---------------------------------------------------------------------------
__global__ __launch_bounds__(64) void final_layer_kernel(
    const float* __restrict__ h, const float* __restrict__ W2,
    const float* __restrict__ Wl2, const float* __restrict__ b2,
    float* __restrict__ sup2, float* __restrict__ x_out)
{
    const int row = blockIdx.x;
    const int lane = threadIdx.x;
    const float* hr = h + (long)row * kH;
    float accW[3] = {0.f, 0.f, 0.f};
    float accL[3] = {0.f, 0.f, 0.f};
#pragma unroll
    for (int kb = 0; kb < kH / 64; ++kb) {
        int k = kb * 64 + lane;
        float v = hr[k];
#pragma unroll
        for (int c = 0; c < 3; ++c) {
            accW[c] = fmaf(v, W2[k * 3 + c], accW[c]);
            accL[c] = fmaf(v, Wl2[k * 3 + c], accL[c]);
        }
    }
#pragma unroll
    for (int off = 32; off > 0; off >>= 1) {
#pragma unroll
        for (int c = 0; c < 3; ++c) {
            accW[c] += __shfl_down(accW[c], off);
            accL[c] += __shfl_down(accL[c], off);
        }
    }
    if (lane == 0) {
#pragma unroll
        for (int c = 0; c < 3; ++c) {
            sup2[row * 3 + c] = accW[c];
            x_out[row * 3 + c] = accL[c] + b2[c];
        }
    }
}

__global__ __launch_bounds__(256) void scatter3_kernel(
    const float* __restrict__ sup2, const int* __restrict__ src,
    const int* __restrict__ dst, const float* __restrict__ ew,
    float* __restrict__ x_out)
{
    int e = blockIdx.x * 256 + threadIdx.x;
    if (e >= kE) return;
    int s = src[e];
    int d = dst[e];
    float w = ew[e];
#pragma unroll
    for (int c = 0; c < 3; ++c)
        atomicAdd(&x_out[(long)d * 3 + c], w * sup2[(long)s * 3 + c]);
}

// ---------------------------------------------------------------------------
extern "C" void kernel_launch(void* const* d_in, const int* in_sizes, int n_in,
                              void* d_out, int out_size, void* d_ws, size_t ws_size,
                              hipStream_t stream)
{
    const float* x    = (const float*)d_in[0];
    const int*   src  = (const int*)d_in[1];
    const int*   dst  = (const int*)d_in[2];
    const float* ew   = (const float*)d_in[3];
    const float* W1   = (const float*)d_in[4];
    const float* Wl1  = (const float*)d_in[5];
    const float* b1   = (const float*)d_in[6];
    const float* blkW  = (const float*)d_in[7];
    const float* blkWl = (const float*)d_in[8];
    const float* blkb  = (const float*)d_in[9];
    const float* W2   = (const float*)d_in[10];
    const float* Wl2  = (const float*)d_in[11];
    const float* b2   = (const float*)d_in[12];

    float* out   = (float*)d_out;
    float* x_out = out;                       // N*3
    float* h     = out + (long)kN * 3;        // N*H fp32 = x_hidden output

    // ---- workspace carve-up (≈136 MB)
    char* w = (char*)d_ws;
    size_t off = 0;
    auto carve = [&](size_t bytes) { char* p = w + off; off = (off + bytes + 255) & ~(size_t)255; return p; };
    unsigned short* supb  = (unsigned short*)carve(12800000UL * 2);
    float*          tpre  = (float*)carve(12800000UL * 4);
    unsigned short* tact  = (unsigned short*)carve(12800000UL * 2);
    unsigned short* hbf   = (unsigned short*)carve(12800000UL * 2);
    unsigned short* w1c   = (unsigned short*)carve(512UL * 1024 * 2);
    unsigned short* blkc  = (unsigned short*)carve(12UL * 512 * 256 * 2);
    int*   e_src  = (int*)carve(kE * 4);
    float* e_w    = (float*)carve(kE * 4);
    int*   counts = (int*)carve(50176 * 4);
    int*   rowptr = (int*)carve(50176 * 4);
    int*   cursor = (int*)carve(50176 * 4);
    int*   bsum   = (int*)carve(64 * 4);
    float* sup2   = (float*)carve((long)kN * 3 * 4);

    // ---- CSR build
    hipMemsetAsync(counts, 0, 50176 * 4, stream);
    hist_kernel<<<(kE + 255) / 256, 256, 0, stream>>>(dst, counts);
    scan1_kernel<<<49, 1024, 0, stream>>>(counts, rowptr, bsum);
    scan2_kernel<<<1, 64, 0, stream>>>(bsum, 49);
    scan3_kernel<<<(kN + 255) / 256, 256, 0, stream>>>(rowptr, bsum, cursor);
    fill_kernel<<<(kE + 255) / 256, 256, 0, stream>>>(src, dst, ew, cursor, e_src, e_w);

    // ---- weight conversion (bf16, concatenated [W|Wl], transposed [col][k])
    cvt_w1_kernel<<<2048, 256, 0, stream>>>(W1, Wl1, w1c);
    cvt_blk_kernel<<<6144, 256, 0, stream>>>(blkW, blkWl, blkc);

    const dim3 gemm_grid(4, (kN + 127) / 128);   // 4 col-tiles x 391 row-tiles
    const int agg_grid = (kN + 3) / 4;

    // ---- Layer 1: h = relu(gconv(x)), K=963 (pad 1024), fp32 A cvt in-kernel
    gemm_dual<true><<<gemm_grid, 256, 0, stream>>>(x, w1c, b1, supb, tpre,
                                                   kN, 1024, kDIN, kDIN);
    agg_kernel<2><<<agg_grid, 256, 0, stream>>>(supb, tpre, rowptr, e_src, e_w, h, hbf);

    // ---- 6 residual blocks x 2 convs
    for (int l = 0; l < 2 * kNBLK; ++l) {
        const unsigned short* A = (l & 1) ? tact : hbf;
        gemm_dual<false><<<gemm_grid, 256, 0, stream>>>(
            A, blkc + (long)l * 512 * 256, blkb + (long)l * 256,
            supb, tpre, kN, 256, 256, 256);
        if (l & 1)
            agg_kernel<1><<<agg_grid, 256, 0, stream>>>(supb, tpre, rowptr, e_src, e_w, h, hbf);
        else
            agg_kernel<0><<<agg_grid, 256, 0, stream>>>(supb, tpre, rowptr, e_src, e_w, nullptr, tact);
    }

    // ---- final layer (fp32)
    final_layer_kernel<<<kN, 64, 0, stream>>>(h, W2, Wl2, b2, sup2, x_out);
    scatter3_kernel<<<(kE + 255) / 256, 256, 0, stream>>>(sup2, src, dst, ew, x_out);
}

// Round 4
// 1454.185 us; speedup vs baseline: 5.2860x; 1.5618x over previous
//
#include <hip/hip_runtime.h>

typedef __attribute__((ext_vector_type(8))) short short8;
typedef __attribute__((ext_vector_type(4))) float f32x4;

constexpr int kN = 50000;
constexpr int kE = 300000;
constexpr int kDIN = 963;
constexpr int kH = 256;
constexpr int kNBLK = 6;

__device__ inline unsigned short f2bf(float f) {
    unsigned u = __float_as_uint(f);
    u = u + 0x7FFFu + ((u >> 16) & 1u);   // RTNE
    return (unsigned short)(u >> 16);
}
__device__ inline float bf2f(unsigned short s) {
    return __uint_as_float(((unsigned)s) << 16);
}

__device__ inline void gload_lds16(const void* g, void* l) {
    __builtin_amdgcn_global_load_lds(
        (const __attribute__((address_space(1))) void*)g,
        (__attribute__((address_space(3))) void*)l, 16, 0, 0);
}

// ---------------------------------------------------------------------------
// Dual GEMM: [supb | tpre] = A(MxK) @ Bt^T, Bt is [512][Kpad] bf16.
// Tile 128 rows x 256 cols, 8 waves (2 row x 4 col), 64x64 per wave,
// mfma_f32_16x16x32_bf16 swapped operands (lane&15 = output row).
// Grid: 782 linear blocks, bijective XCD-chunked swizzle (col fastest, then
// row) so blocks sharing an A panel run on the same XCD -> A fetched ~once.
// LDS: A[128][64] + B[256][64] bf16, XOR-swizzled (chunk16 ^= row&7),
// global_load_lds with pre-swizzled global source.
// ---------------------------------------------------------------------------
template<bool ACVT>
__global__ __launch_bounds__(512) void gemm_dual(
    const void* __restrict__ Av, const unsigned short* __restrict__ Bt,
    const float* __restrict__ bias,
    unsigned short* __restrict__ supb, float* __restrict__ tpre,
    int M, int Kpad, int Kvalid, int Astride)
{
    __shared__ __align__(16) char smem[49152];
    char* As = smem;             // 128 rows x 128 B (64 bf16 k)
    char* Bs = smem + 16384;     // 256 cols x 128 B

    const int tid = threadIdx.x;
    const int wid = tid >> 6;
    const int lane = tid & 63;
    const int wr = wid >> 2, wc = wid & 3;

    // bijective XCD-chunked tile decode (m204)
    const int nwg = gridDim.x;
    const int q = nwg >> 3, r = nwg & 7;
    const int xcd = blockIdx.x & 7, idx = blockIdx.x >> 3;
    const int t = (xcd < r ? xcd * (q + 1) : r * (q + 1) + (xcd - r) * q) + idx;
    const int r0 = (t >> 1) * 128;
    const int c0 = (t & 1) * 256;

    f32x4 acc[4][4];
#pragma unroll
    for (int i = 0; i < 4; ++i)
#pragma unroll
        for (int j = 0; j < 4; ++j) acc[i][j] = f32x4{0.f, 0.f, 0.f, 0.f};

    const int l_row = lane >> 3;      // 0..7
    const int l_c   = lane & 7;       // 16B chunk

    for (int k0 = 0; k0 < Kpad; k0 += 64) {
        // ---- stage B (weights): wave covers 32 tile-cols
#pragma unroll
        for (int p = 0; p < 4; ++p) {
            int row = wid * 32 + p * 8 + l_row;
            int csw = l_c ^ (row & 7);
            const unsigned short* g = Bt + (long)(c0 + row) * Kpad + k0 + csw * 8;
            gload_lds16(g, Bs + (wid * 32 + p * 8) * 128);
        }
        if (!ACVT) {
            // ---- stage A (bf16 activations): wave covers 16 rows
            const unsigned short* A = (const unsigned short*)Av;
#pragma unroll
            for (int p = 0; p < 2; ++p) {
                int row = wid * 16 + p * 8 + l_row;
                int grow = r0 + row; if (grow >= M) grow = M - 1;
                int csw = l_c ^ (row & 7);
                const unsigned short* g = A + (long)grow * Astride + k0 + csw * 8;
                gload_lds16(g, As + (wid * 16 + p * 8) * 128);
            }
        } else {
            // reg-stage fp32 A -> bf16 LDS (layer 1: x, K=963, Kpad=1024)
            const int row = tid >> 2;
            const int kq = tid & 3;
            int grow = r0 + row; if (grow >= M) grow = M - 1;
            const float* ar = (const float*)Av + (long)grow * Astride;
#pragma unroll
            for (int j = 0; j < 2; ++j) {
                int k16 = kq * 2 + j;
                short8 v;
#pragma unroll
                for (int ii = 0; ii < 8; ++ii) {
                    int k = k0 + k16 * 8 + ii;
                    float f = (k < Kvalid) ? ar[k] : 0.f;
                    v[ii] = (short)f2bf(f);
                }
                *(short8*)(As + row * 128 + ((k16 ^ (row & 7)) << 4)) = v;
            }
        }
        __syncthreads();

        // ---- compute: 2 x (8 ds_read_b128 + 16 MFMA)
#pragma unroll
        for (int kk = 0; kk < 2; ++kk) {
            short8 af[4], bfr[4];
            const int kg = kk * 4 + (lane >> 4);   // logical 16B chunk 0..7
#pragma unroll
            for (int nr = 0; nr < 4; ++nr) {
                int row = wr * 64 + nr * 16 + (lane & 15);
                af[nr] = *(const short8*)(As + row * 128 + ((kg ^ (row & 7)) << 4));
            }
#pragma unroll
            for (int mc = 0; mc < 4; ++mc) {
                int row = wc * 64 + mc * 16 + (lane & 15);
                bfr[mc] = *(const short8*)(Bs + row * 128 + ((kg ^ (row & 7)) << 4));
            }
#pragma unroll
            for (int mc = 0; mc < 4; ++mc)
#pragma unroll
                for (int nr = 0; nr < 4; ++nr)
                    acc[mc][nr] = __builtin_amdgcn_mfma_f32_16x16x32_bf16(
                        bfr[mc], af[nr], acc[mc][nr], 0, 0, 0);
        }
        __syncthreads();
    }

    // ---- epilogue
    const bool isSup = (c0 == 0);
#pragma unroll
    for (int mc = 0; mc < 4; ++mc) {
        const int lcol = wc * 64 + mc * 16 + ((lane >> 4) << 2);
#pragma unroll
        for (int nr = 0; nr < 4; ++nr) {
            const int rr = r0 + wr * 64 + nr * 16 + (lane & 15);
            if (rr >= M) continue;
            f32x4 v = acc[mc][nr];
            if (isSup) {
                uint2 pk;
                pk.x = (unsigned)f2bf(v[0]) | ((unsigned)f2bf(v[1]) << 16);
                pk.y = (unsigned)f2bf(v[2]) | ((unsigned)f2bf(v[3]) << 16);
                *(uint2*)(supb + (long)rr * 256 + lcol) = pk;
            } else {
                const f32x4 b4 = *(const f32x4*)(bias + lcol);
                v += b4;
                *(f32x4*)(tpre + (long)rr * 256 + lcol) = v;
            }
        }
    }
}

// ---------------------------------------------------------------------------
// CSR-gather aggregation, fused epilogue. One wave per node, lane owns 4 cols.
// MODE 0: tact_bf = bf16(relu(tpre + agg))
// MODE 1: h = (h + relu(tpre + agg)) * 0.5 ; hbf = bf16(h)
// MODE 2: h = relu(tpre + agg)             ; hbf = bf16(h)
// ---------------------------------------------------------------------------
template<int MODE>
__global__ __launch_bounds__(256) void agg_kernel(
    const unsigned short* __restrict__ supb, const float* __restrict__ tpre,
    const int* __restrict__ rowptr, const int* __restrict__ e_src,
    const float* __restrict__ e_w,
    float* __restrict__ h, unsigned short* __restrict__ obf)
{
    const int wid = threadIdx.x >> 6, lane = threadIdx.x & 63;
    const long node = (long)blockIdx.x * 4 + wid;
    if (node >= kN) return;
    const int c0 = lane << 2;

    f32x4 a = *(const f32x4*)(tpre + node * 256 + c0);
    int b = rowptr[node];
    const int e = rowptr[node + 1];
    for (; b < e; ++b) {
        const int s = e_src[b];
        const float w = e_w[b];
        ushort4 sv = *(const ushort4*)(supb + (long)s * 256 + c0);
        a[0] += w * bf2f(sv.x); a[1] += w * bf2f(sv.y);
        a[2] += w * bf2f(sv.z); a[3] += w * bf2f(sv.w);
    }
    a[0] = fmaxf(a[0], 0.f); a[1] = fmaxf(a[1], 0.f);
    a[2] = fmaxf(a[2], 0.f); a[3] = fmaxf(a[3], 0.f);

    f32x4 r = a;
    if (MODE == 1) {
        f32x4 hv = *(const f32x4*)(h + node * 256 + c0);
        r = (hv + a) * 0.5f;
    }
    if (MODE == 1 || MODE == 2)
        *(f32x4*)(h + node * 256 + c0) = r;

    uint2 pk;
    pk.x = (unsigned)f2bf(r[0]) | ((unsigned)f2bf(r[1]) << 16);
    pk.y = (unsigned)f2bf(r[2]) | ((unsigned)f2bf(r[3]) << 16);
    *(uint2*)(obf + node * 256 + c0) = pk;
}

// ---------------------------------------------------------------------------
// Weight conversion
// ---------------------------------------------------------------------------
__global__ __launch_bounds__(256) void cvt_w1_kernel(
    const float* __restrict__ W1, const float* __restrict__ Wl1,
    unsigned short* __restrict__ out)
{
    int idx = blockIdx.x * 256 + threadIdx.x;       // 512*1024
    if (idx >= 512 * 1024) return;
    int c = idx >> 10, k = idx & 1023;
    float v = 0.f;
    if (k < kDIN) v = (c < 256) ? W1[(long)k * 256 + c] : Wl1[(long)k * 256 + (c - 256)];
    out[idx] = f2bf(v);
}

__global__ __launch_bounds__(256) void cvt_blk_kernel(
    const float* __restrict__ blkW, const float* __restrict__ blkWl,
    unsigned short* __restrict__ out)
{
    int idx = blockIdx.x * 256 + threadIdx.x;       // 12*512*256
    if (idx >= 12 * 512 * 256) return;
    int l = idx >> 17;
    int rem = idx & 131071;
    int c = rem >> 8, k = rem & 255;
    float v = (c < 256) ? blkW[((long)l * 256 + k) * 256 + c]
                        : blkWl[((long)l * 256 + k) * 256 + (c - 256)];
    out[idx] = f2bf(v);
}

// ---------------------------------------------------------------------------
// CSR build: histogram -> hierarchical exclusive scan -> fill
// ---------------------------------------------------------------------------
__global__ __launch_bounds__(256) void hist_kernel(const int* __restrict__ dst,
                                                   int* __restrict__ counts)
{
    int e = blockIdx.x * 256 + threadIdx.x;
    if (e < kE) atomicAdd(&counts[dst[e]], 1);
}

__global__ __launch_bounds__(1024) void scan1_kernel(
    const int* __restrict__ counts, int* __restrict__ rowptr, int* __restrict__ bsum)
{
    __shared__ int s[1024];
    const int tid = threadIdx.x;
    const int g = blockIdx.x * 1024 + tid;
    const int v = (g < kN) ? counts[g] : 0;
    s[tid] = v; __syncthreads();
    for (int off = 1; off < 1024; off <<= 1) {
        int tv = (tid >= off) ? s[tid - off] : 0;
        __syncthreads();
        s[tid] += tv;
        __syncthreads();
    }
    if (g < kN) rowptr[g] = s[tid] - v;   // block-local exclusive
    if (tid == 1023) bsum[blockIdx.x] = s[1023];
}

__global__ __launch_bounds__(64) void scan2_kernel(int* __restrict__ bsum, int nb)
{
    __shared__ int s[64];
    const int tid = threadIdx.x;
    const int v = (tid < nb) ? bsum[tid] : 0;
    s[tid] = v; __syncthreads();
    for (int off = 1; off < 64; off <<= 1) {
        int tv = (tid >= off) ? s[tid - off] : 0;
        __syncthreads();
        s[tid] += tv;
        __syncthreads();
    }
    if (tid < nb) bsum[tid] = s[tid] - v;  // exclusive
}

__global__ __launch_bounds__(256) void scan3_kernel(
    int* __restrict__ rowptr, const int* __restrict__ bsum, int* __restrict__ cursor)
{
    int g = blockIdx.x * 256 + threadIdx.x;
    if (g < kN) {
        int r = rowptr[g] + bsum[g >> 10];
        rowptr[g] = r;
        cursor[g] = r;
    }
    if (g == 0) rowptr[kN] = kE;
}

__global__ __launch_bounds__(256) void fill_kernel(
    const int* __restrict__ src, const int* __restrict__ dst,
    const float* __restrict__ ew, int* __restrict__ cursor,
    int* __restrict__ e_src, float* __restrict__ e_w)
{
    int e = blockIdx.x * 256 + threadIdx.x;
    if (e >= kE) return;
    int d = dst[e];
    int pos = atomicAdd(&cursor[d], 1);
    e_src[pos] = src[e];
    e_w[pos] = ew[e];
}

// ---------------------------------------------------------------------------
// Final layer (fp32, DOUT=3): one wave per row
// ---------------------------------------------------------------------------
__global__ __launch_bounds__(64) void final_layer_kernel(
    const float* __restrict__ h, const float* __restrict__ W2,
    const float* __restrict__ Wl2, const float* __restrict__ b2,
    float* __restrict__ sup2, float* __restrict__ x_out)
{
    const int row = blockIdx.x;
    const int lane = threadIdx.x;
    const float* hr = h + (long)row * kH;
    float accW[3] = {0.f, 0.f, 0.f};
    float accL[3] = {0.f, 0.f, 0.f};
#pragma unroll
    for (int kb = 0; kb < kH / 64; ++kb) {
        int k = kb * 64 + lane;
        float v = hr[k];
#pragma unroll
        for (int c = 0; c < 3; ++c) {
            accW[c] = fmaf(v, W2[k * 3 + c], accW[c]);
            accL[c] = fmaf(v, Wl2[k * 3 + c], accL[c]);
        }
    }
#pragma unroll
    for (int off = 32; off > 0; off >>= 1) {
#pragma unroll
        for (int c = 0; c < 3; ++c) {
            accW[c] += __shfl_down(accW[c], off);
            accL[c] += __shfl_down(accL[c], off);
        }
    }
    if (lane == 0) {
#pragma unroll
        for (int c = 0; c < 3; ++c) {
            sup2[row * 3 + c] = accW[c];
            x_out[row * 3 + c] = accL[c] + b2[c];
        }
    }
}

__global__ __launch_bounds__(256) void scatter3_kernel(
    const float* __restrict__ sup2, const int* __restrict__ src,
    const int* __restrict__ dst, const float* __restrict__ ew,
    float* __restrict__ x_out)
{
    int e = blockIdx.x * 256 + threadIdx.x;
    if (e >= kE) return;
    int s = src[e];
    int d = dst[e];
    float w = ew[e];
#pragma unroll
    for (int c = 0; c < 3; ++c)
        atomicAdd(&x_out[(long)d * 3 + c], w * sup2[(long)s * 3 + c]);
}

// ---------------------------------------------------------------------------
extern "C" void kernel_launch(void* const* d_in, const int* in_sizes, int n_in,
                              void* d_out, int out_size, void* d_ws, size_t ws_size,
                              hipStream_t stream)
{
    const float* x    = (const float*)d_in[0];
    const int*   src  = (const int*)d_in[1];
    const int*   dst  = (const int*)d_in[2];
    const float* ew   = (const float*)d_in[3];
    const float* W1   = (const float*)d_in[4];
    const float* Wl1  = (const float*)d_in[5];
    const float* b1   = (const float*)d_in[6];
    const float* blkW  = (const float*)d_in[7];
    const float* blkWl = (const float*)d_in[8];
    const float* blkb  = (const float*)d_in[9];
    const float* W2   = (const float*)d_in[10];
    const float* Wl2  = (const float*)d_in[11];
    const float* b2   = (const float*)d_in[12];

    float* out   = (float*)d_out;
    float* x_out = out;                       // N*3
    float* h     = out + (long)kN * 3;        // N*H fp32 = x_hidden output

    // ---- workspace carve-up
    char* w = (char*)d_ws;
    size_t off = 0;
    auto carve = [&](size_t bytes) { char* p = w + off; off = (off + bytes + 255) & ~(size_t)255; return p; };
    unsigned short* supb  = (unsigned short*)carve(12800000UL * 2);
    float*          tpre  = (float*)carve(12800000UL * 4);
    unsigned short* tact  = (unsigned short*)carve(12800000UL * 2);
    unsigned short* hbf   = (unsigned short*)carve(12800000UL * 2);
    unsigned short* w1c   = (unsigned short*)carve(512UL * 1024 * 2);
    unsigned short* blkc  = (unsigned short*)carve(12UL * 512 * 256 * 2);
    int*   e_src  = (int*)carve(kE * 4);
    float* e_w    = (float*)carve(kE * 4);
    int*   counts = (int*)carve(50176 * 4);
    int*   rowptr = (int*)carve(50176 * 4);
    int*   cursor = (int*)carve(50176 * 4);
    int*   bsum   = (int*)carve(64 * 4);
    float* sup2   = (float*)carve((long)kN * 3 * 4);

    // ---- CSR build
    hipMemsetAsync(counts, 0, 50176 * 4, stream);
    hist_kernel<<<(kE + 255) / 256, 256, 0, stream>>>(dst, counts);
    scan1_kernel<<<49, 1024, 0, stream>>>(counts, rowptr, bsum);
    scan2_kernel<<<1, 64, 0, stream>>>(bsum, 49);
    scan3_kernel<<<(kN + 255) / 256, 256, 0, stream>>>(rowptr, bsum, cursor);
    fill_kernel<<<(kE + 255) / 256, 256, 0, stream>>>(src, dst, ew, cursor, e_src, e_w);

    // ---- weight conversion (bf16, concatenated [W|Wl], transposed [col][k])
    cvt_w1_kernel<<<2048, 256, 0, stream>>>(W1, Wl1, w1c);
    cvt_blk_kernel<<<6144, 256, 0, stream>>>(blkW, blkWl, blkc);

    const int gemm_grid = 2 * ((kN + 127) / 128);   // 782 linear (col fastest)
    const int agg_grid = (kN + 3) / 4;

    // ---- Layer 1: h = relu(gconv(x)), K=963 (pad 1024), fp32 A cvt in-kernel
    gemm_dual<true><<<gemm_grid, 512, 0, stream>>>(x, w1c, b1, supb, tpre,
                                                   kN, 1024, kDIN, kDIN);
    agg_kernel<2><<<agg_grid, 256, 0, stream>>>(supb, tpre, rowptr, e_src, e_w, h, hbf);

    // ---- 6 residual blocks x 2 convs
    for (int l = 0; l < 2 * kNBLK; ++l) {
        const unsigned short* A = (l & 1) ? tact : hbf;
        gemm_dual<false><<<gemm_grid, 512, 0, stream>>>(
            A, blkc + (long)l * 512 * 256, blkb + (long)l * 256,
            supb, tpre, kN, 256, 256, 256);
        if (l & 1)
            agg_kernel<1><<<agg_grid, 256, 0, stream>>>(supb, tpre, rowptr, e_src, e_w, h, hbf);
        else
            agg_kernel<0><<<agg_grid, 256, 0, stream>>>(supb, tpre, rowptr, e_src, e_w, nullptr, tact);
    }

    // ---- final layer (fp32)
    final_layer_kernel<<<kN, 64, 0, stream>>>(h, W2, Wl2, b2, sup2, x_out);
    scatter3_kernel<<<(kE + 255) / 256, 256, 0, stream>>>(sup2, src, dst, ew, x_out);
}

// Round 5
// 1305.669 us; speedup vs baseline: 5.8873x; 1.1137x over previous
//
#include <hip/hip_runtime.h>

typedef __attribute__((ext_vector_type(8))) short short8;
typedef __attribute__((ext_vector_type(4))) float f32x4;

constexpr int kN = 50000;
constexpr int kE = 300000;
constexpr int kDIN = 963;
constexpr int kH = 256;
constexpr int kNBLK = 6;

__device__ inline unsigned short f2bf(float f) {
    unsigned u = __float_as_uint(f);
    u = u + 0x7FFFu + ((u >> 16) & 1u);   // RTNE
    return (unsigned short)(u >> 16);
}
__device__ inline float bf2f(unsigned short s) {
    return __uint_as_float(((unsigned)s) << 16);
}

__device__ inline void gload_lds16(const void* g, void* l) {
    __builtin_amdgcn_global_load_lds(
        (const __attribute__((address_space(1))) void*)g,
        (__attribute__((address_space(3))) void*)l, 16, 0, 0);
}

// ---------------------------------------------------------------------------
// Dual GEMM: [supb | tpreb] = A(MxK) @ Bt^T, Bt is [512][Kpad] bf16.
// Tile 128 rows x 256 cols, 8 waves (2 row x 4 col), 64x64 per wave,
// mfma_f32_16x16x32_bf16 swapped operands (lane&15 = output row).
// Grid: 782 linear blocks, bijective XCD-chunked swizzle (col fastest) so
// blocks sharing an A panel run on the same XCD -> A fetched ~once.
// Epilogue: fp32 acc staged through LDS (32x256, XOR-swizzled), emitted as
// 256B-contiguous 128B-aligned bf16 stores -> no partial-line RFO.
// ---------------------------------------------------------------------------
template<bool ACVT>
__global__ __launch_bounds__(512) void gemm_dual(
    const void* __restrict__ Av, const unsigned short* __restrict__ Bt,
    const float* __restrict__ bias,
    unsigned short* __restrict__ supb, unsigned short* __restrict__ tpreb,
    int M, int Kpad, int Kvalid, int Astride)
{
    __shared__ __align__(16) char smem[49152];
    char* As = smem;             // 128 rows x 128 B (64 bf16 k)
    char* Bs = smem + 16384;     // 256 cols x 128 B

    const int tid = threadIdx.x;
    const int wid = tid >> 6;
    const int lane = tid & 63;
    const int wr = wid >> 2, wc = wid & 3;

    // bijective XCD-chunked tile decode (m204)
    const int nwg = gridDim.x;
    const int q = nwg >> 3, r = nwg & 7;
    const int xcd = blockIdx.x & 7, idx = blockIdx.x >> 3;
    const int t = (xcd < r ? xcd * (q + 1) : r * (q + 1) + (xcd - r) * q) + idx;
    const int r0 = (t >> 1) * 128;
    const int c0 = (t & 1) * 256;

    f32x4 acc[4][4];
#pragma unroll
    for (int i = 0; i < 4; ++i)
#pragma unroll
        for (int j = 0; j < 4; ++j) acc[i][j] = f32x4{0.f, 0.f, 0.f, 0.f};

    const int l_row = lane >> 3;      // 0..7
    const int l_c   = lane & 7;       // 16B chunk

    for (int k0 = 0; k0 < Kpad; k0 += 64) {
        // ---- stage B (weights): wave covers 32 tile-cols
#pragma unroll
        for (int p = 0; p < 4; ++p) {
            int row = wid * 32 + p * 8 + l_row;
            int csw = l_c ^ (row & 7);
            const unsigned short* g = Bt + (long)(c0 + row) * Kpad + k0 + csw * 8;
            gload_lds16(g, Bs + (wid * 32 + p * 8) * 128);
        }
        if (!ACVT) {
            // ---- stage A (bf16 activations): wave covers 16 rows
            const unsigned short* A = (const unsigned short*)Av;
#pragma unroll
            for (int p = 0; p < 2; ++p) {
                int row = wid * 16 + p * 8 + l_row;
                int grow = r0 + row; if (grow >= M) grow = M - 1;
                int csw = l_c ^ (row & 7);
                const unsigned short* g = A + (long)grow * Astride + k0 + csw * 8;
                gload_lds16(g, As + (wid * 16 + p * 8) * 128);
            }
        } else {
            // reg-stage fp32 A -> bf16 LDS (layer 1: x, K=963, Kpad=1024)
            const int row = tid >> 2;
            const int kq = tid & 3;
            int grow = r0 + row; if (grow >= M) grow = M - 1;
            const float* ar = (const float*)Av + (long)grow * Astride;
#pragma unroll
            for (int j = 0; j < 2; ++j) {
                int k16 = kq * 2 + j;
                short8 v;
#pragma unroll
                for (int ii = 0; ii < 8; ++ii) {
                    int k = k0 + k16 * 8 + ii;
                    float f = (k < Kvalid) ? ar[k] : 0.f;
                    v[ii] = (short)f2bf(f);
                }
                *(short8*)(As + row * 128 + ((k16 ^ (row & 7)) << 4)) = v;
            }
        }
        __syncthreads();

        // ---- compute: 2 x (8 ds_read_b128 + 16 MFMA)
#pragma unroll
        for (int kk = 0; kk < 2; ++kk) {
            short8 af[4], bfr[4];
            const int kg = kk * 4 + (lane >> 4);   // logical 16B chunk 0..7
#pragma unroll
            for (int nr = 0; nr < 4; ++nr) {
                int row = wr * 64 + nr * 16 + (lane & 15);
                af[nr] = *(const short8*)(As + row * 128 + ((kg ^ (row & 7)) << 4));
            }
#pragma unroll
            for (int mc = 0; mc < 4; ++mc) {
                int row = wc * 64 + mc * 16 + (lane & 15);
                bfr[mc] = *(const short8*)(Bs + row * 128 + ((kg ^ (row & 7)) << 4));
            }
#pragma unroll
            for (int mc = 0; mc < 4; ++mc)
#pragma unroll
                for (int nr = 0; nr < 4; ++nr)
                    acc[mc][nr] = __builtin_amdgcn_mfma_f32_16x16x32_bf16(
                        bfr[mc], af[nr], acc[mc][nr], 0, 0, 0);
        }
        __syncthreads();
    }

    // ---- epilogue: LDS-staged, full-line bf16 stores (no RFO)
    const bool isSup = (c0 == 0);
    unsigned short* outp = isSup ? supb : tpreb;
    float* eL = (float*)smem;                 // 32 x 256 fp32 = 32 KB
    const int wrow = wr * 16 + (lane & 15);   // 0..31
    const int qc = (lane >> 4) << 2;          // col quad base within 16

    for (int nr = 0; nr < 4; ++nr) {
        __syncthreads();
#pragma unroll
        for (int mc = 0; mc < 4; ++mc) {
            const int col = wc * 64 + mc * 16 + qc;
            f32x4 v = acc[mc][nr];
            if (!isSup) v += *(const f32x4*)(bias + col);
            const int c16 = col >> 2;                       // fp32 16B chunk
            *(f32x4*)(eL + wrow * 256 + ((c16 ^ wrow) << 2)) = v;
        }
        __syncthreads();
        const int tr = tid >> 4, j = tid & 15;
        const int gr = r0 + (tr >> 4) * 64 + nr * 16 + (tr & 15);
        if (gr < M) {
#pragma unroll
            for (int p = 0; p < 2; ++p) {
                const int u = j + 16 * p;                   // bf16 16B unit
                f32x4 lo = *(const f32x4*)(eL + tr * 256 + (((2 * u) ^ tr) << 2));
                f32x4 hi = *(const f32x4*)(eL + tr * 256 + (((2 * u + 1) ^ tr) << 2));
                uint4 pk;
                pk.x = (unsigned)f2bf(lo[0]) | ((unsigned)f2bf(lo[1]) << 16);
                pk.y = (unsigned)f2bf(lo[2]) | ((unsigned)f2bf(lo[3]) << 16);
                pk.z = (unsigned)f2bf(hi[0]) | ((unsigned)f2bf(hi[1]) << 16);
                pk.w = (unsigned)f2bf(hi[2]) | ((unsigned)f2bf(hi[3]) << 16);
                *(uint4*)(outp + (long)gr * 256 + u * 8) = pk;
            }
        }
    }
}

// ---------------------------------------------------------------------------
// CSR-gather aggregation, fused epilogue. One wave per node, lane owns 4 cols.
// MODE 0: tact_bf = bf16(relu(tpre + agg))
// MODE 1: h = (h + relu(tpre + agg)) * 0.5 ; hbf = bf16(h)
// MODE 2: h = relu(tpre + agg)             ; hbf = bf16(h)
// ---------------------------------------------------------------------------
template<int MODE>
__global__ __launch_bounds__(256) void agg_kernel(
    const unsigned short* __restrict__ supb, const unsigned short* __restrict__ tpreb,
    const int* __restrict__ rowptr, const int* __restrict__ e_src,
    const float* __restrict__ e_w,
    float* __restrict__ h, unsigned short* __restrict__ obf)
{
    const int wid = threadIdx.x >> 6, lane = threadIdx.x & 63;
    const long node = (long)blockIdx.x * 4 + wid;
    if (node >= kN) return;
    const int c0 = lane << 2;

    ushort4 tv = *(const ushort4*)(tpreb + node * 256 + c0);
    f32x4 a = {bf2f(tv.x), bf2f(tv.y), bf2f(tv.z), bf2f(tv.w)};
    int b = rowptr[node];
    const int e = rowptr[node + 1];
    for (; b < e; ++b) {
        const int s = e_src[b];
        const float w = e_w[b];
        ushort4 sv = *(const ushort4*)(supb + (long)s * 256 + c0);
        a[0] += w * bf2f(sv.x); a[1] += w * bf2f(sv.y);
        a[2] += w * bf2f(sv.z); a[3] += w * bf2f(sv.w);
    }
    a[0] = fmaxf(a[0], 0.f); a[1] = fmaxf(a[1], 0.f);
    a[2] = fmaxf(a[2], 0.f); a[3] = fmaxf(a[3], 0.f);

    f32x4 r = a;
    if (MODE == 1) {
        f32x4 hv = *(const f32x4*)(h + node * 256 + c0);
        r = (hv + a) * 0.5f;
    }
    if (MODE == 1 || MODE == 2)
        *(f32x4*)(h + node * 256 + c0) = r;

    uint2 pk;
    pk.x = (unsigned)f2bf(r[0]) | ((unsigned)f2bf(r[1]) << 16);
    pk.y = (unsigned)f2bf(r[2]) | ((unsigned)f2bf(r[3]) << 16);
    *(uint2*)(obf + node * 256 + c0) = pk;
}

// ---------------------------------------------------------------------------
// Weight conversion
// ---------------------------------------------------------------------------
__global__ __launch_bounds__(256) void cvt_w1_kernel(
    const float* __restrict__ W1, const float* __restrict__ Wl1,
    unsigned short* __restrict__ out)
{
    int idx = blockIdx.x * 256 + threadIdx.x;       // 512*1024
    if (idx >= 512 * 1024) return;
    int c = idx >> 10, k = idx & 1023;
    float v = 0.f;
    if (k < kDIN) v = (c < 256) ? W1[(long)k * 256 + c] : Wl1[(long)k * 256 + (c - 256)];
    out[idx] = f2bf(v);
}

__global__ __launch_bounds__(256) void cvt_blk_kernel(
    const float* __restrict__ blkW, const float* __restrict__ blkWl,
    unsigned short* __restrict__ out)
{
    int idx = blockIdx.x * 256 + threadIdx.x;       // 12*512*256
    if (idx >= 12 * 512 * 256) return;
    int l = idx >> 17;
    int rem = idx & 131071;
    int c = rem >> 8, k = rem & 255;
    float v = (c < 256) ? blkW[((long)l * 256 + k) * 256 + c]
                        : blkWl[((long)l * 256 + k) * 256 + (c - 256)];
    out[idx] = f2bf(v);
}

// ---------------------------------------------------------------------------
// CSR build: histogram -> hierarchical exclusive scan -> fill
// ---------------------------------------------------------------------------
__global__ __launch_bounds__(256) void hist_kernel(const int* __restrict__ dst,
                                                   int* __restrict__ counts)
{
    int e = blockIdx.x * 256 + threadIdx.x;
    if (e < kE) atomicAdd(&counts[dst[e]], 1);
}

__global__ __launch_bounds__(1024) void scan1_kernel(
    const int* __restrict__ counts, int* __restrict__ rowptr, int* __restrict__ bsum)
{
    __shared__ int s[1024];
    const int tid = threadIdx.x;
    const int g = blockIdx.x * 1024 + tid;
    const int v = (g < kN) ? counts[g] : 0;
    s[tid] = v; __syncthreads();
    for (int off = 1; off < 1024; off <<= 1) {
        int tv = (tid >= off) ? s[tid - off] : 0;
        __syncthreads();
        s[tid] += tv;
        __syncthreads();
    }
    if (g < kN) rowptr[g] = s[tid] - v;   // block-local exclusive
    if (tid == 1023) bsum[blockIdx.x] = s[1023];
}

__global__ __launch_bounds__(64) void scan2_kernel(int* __restrict__ bsum, int nb)
{
    __shared__ int s[64];
    const int tid = threadIdx.x;
    const int v = (tid < nb) ? bsum[tid] : 0;
    s[tid] = v; __syncthreads();
    for (int off = 1; off < 64; off <<= 1) {
        int tv = (tid >= off) ? s[tid - off] : 0;
        __syncthreads();
        s[tid] += tv;
        __syncthreads();
    }
    if (tid < nb) bsum[tid] = s[tid] - v;  // exclusive
}

__global__ __launch_bounds__(256) void scan3_kernel(
    int* __restrict__ rowptr, const int* __restrict__ bsum, int* __restrict__ cursor)
{
    int g = blockIdx.x * 256 + threadIdx.x;
    if (g < kN) {
        int r = rowptr[g] + bsum[g >> 10];
        rowptr[g] = r;
        cursor[g] = r;
    }
    if (g == 0) rowptr[kN] = kE;
}

__global__ __launch_bounds__(256) void fill_kernel(
    const int* __restrict__ src, const int* __restrict__ dst,
    const float* __restrict__ ew, int* __restrict__ cursor,
    int* __restrict__ e_src, float* __restrict__ e_w)
{
    int e = blockIdx.x * 256 + threadIdx.x;
    if (e >= kE) return;
    int d = dst[e];
    int pos = atomicAdd(&cursor[d], 1);
    e_src[pos] = src[e];
    e_w[pos] = ew[e];
}

// ---------------------------------------------------------------------------
// Final layer (fp32, DOUT=3): one wave per row
// ---------------------------------------------------------------------------
__global__ __launch_bounds__(64) void final_layer_kernel(
    const float* __restrict__ h, const float* __restrict__ W2,
    const float* __restrict__ Wl2, const float* __restrict__ b2,
    float* __restrict__ sup2, float* __restrict__ x_out)
{
    const int row = blockIdx.x;
    const int lane = threadIdx.x;
    const float* hr = h + (long)row * kH;
    float accW[3] = {0.f, 0.f, 0.f};
    float accL[3] = {0.f, 0.f, 0.f};
#pragma unroll
    for (int kb = 0; kb < kH / 64; ++kb) {
        int k = kb * 64 + lane;
        float v = hr[k];
#pragma unroll
        for (int c = 0; c < 3; ++c) {
            accW[c] = fmaf(v, W2[k * 3 + c], accW[c]);
            accL[c] = fmaf(v, Wl2[k * 3 + c], accL[c]);
        }
    }
#pragma unroll
    for (int off = 32; off > 0; off >>= 1) {
#pragma unroll
        for (int c = 0; c < 3; ++c) {
            accW[c] += __shfl_down(accW[c], off);
            accL[c] += __shfl_down(accL[c], off);
        }
    }
    if (lane == 0) {
#pragma unroll
        for (int c = 0; c < 3; ++c) {
            sup2[row * 3 + c] = accW[c];
            x_out[row * 3 + c] = accL[c] + b2[c];
        }
    }
}

__global__ __launch_bounds__(256) void scatter3_kernel(
    const float* __restrict__ sup2, const int* __restrict__ src,
    const int* __restrict__ dst, const float* __restrict__ ew,
    float* __restrict__ x_out)
{
    int e = blockIdx.x * 256 + threadIdx.x;
    if (e >= kE) return;
    int s = src[e];
    int d = dst[e];
    float w = ew[e];
#pragma unroll
    for (int c = 0; c < 3; ++c)
        atomicAdd(&x_out[(long)d * 3 + c], w * sup2[(long)s * 3 + c]);
}

// ---------------------------------------------------------------------------
extern "C" void kernel_launch(void* const* d_in, const int* in_sizes, int n_in,
                              void* d_out, int out_size, void* d_ws, size_t ws_size,
                              hipStream_t stream)
{
    const float* x    = (const float*)d_in[0];
    const int*   src  = (const int*)d_in[1];
    const int*   dst  = (const int*)d_in[2];
    const float* ew   = (const float*)d_in[3];
    const float* W1   = (const float*)d_in[4];
    const float* Wl1  = (const float*)d_in[5];
    const float* b1   = (const float*)d_in[6];
    const float* blkW  = (const float*)d_in[7];
    const float* blkWl = (const float*)d_in[8];
    const float* blkb  = (const float*)d_in[9];
    const float* W2   = (const float*)d_in[10];
    const float* Wl2  = (const float*)d_in[11];
    const float* b2   = (const float*)d_in[12];

    float* out   = (float*)d_out;
    float* x_out = out;                       // N*3
    float* h     = out + (long)kN * 3;        // N*H fp32 = x_hidden output

    // ---- workspace carve-up
    char* w = (char*)d_ws;
    size_t off = 0;
    auto carve = [&](size_t bytes) { char* p = w + off; off = (off + bytes + 255) & ~(size_t)255; return p; };
    unsigned short* supb  = (unsigned short*)carve(12800000UL * 2);
    unsigned short* tpreb = (unsigned short*)carve(12800000UL * 2);
    unsigned short* tact  = (unsigned short*)carve(12800000UL * 2);
    unsigned short* hbf   = (unsigned short*)carve(12800000UL * 2);
    unsigned short* w1c   = (unsigned short*)carve(512UL * 1024 * 2);
    unsigned short* blkc  = (unsigned short*)carve(12UL * 512 * 256 * 2);
    int*   e_src  = (int*)carve(kE * 4);
    float* e_w    = (float*)carve(kE * 4);
    int*   counts = (int*)carve(50176 * 4);
    int*   rowptr = (int*)carve(50176 * 4);
    int*   cursor = (int*)carve(50176 * 4);
    int*   bsum   = (int*)carve(64 * 4);
    float* sup2   = (float*)carve((long)kN * 3 * 4);

    // ---- CSR build
    hipMemsetAsync(counts, 0, 50176 * 4, stream);
    hist_kernel<<<(kE + 255) / 256, 256, 0, stream>>>(dst, counts);
    scan1_kernel<<<49, 1024, 0, stream>>>(counts, rowptr, bsum);
    scan2_kernel<<<1, 64, 0, stream>>>(bsum, 49);
    scan3_kernel<<<(kN + 255) / 256, 256, 0, stream>>>(rowptr, bsum, cursor);
    fill_kernel<<<(kE + 255) / 256, 256, 0, stream>>>(src, dst, ew, cursor, e_src, e_w);

    // ---- weight conversion (bf16, concatenated [W|Wl], transposed [col][k])
    cvt_w1_kernel<<<2048, 256, 0, stream>>>(W1, Wl1, w1c);
    cvt_blk_kernel<<<6144, 256, 0, stream>>>(blkW, blkWl, blkc);

    const int gemm_grid = 2 * ((kN + 127) / 128);   // 782 linear (col fastest)
    const int agg_grid = (kN + 3) / 4;

    // ---- Layer 1: h = relu(gconv(x)), K=963 (pad 1024), fp32 A cvt in-kernel
    gemm_dual<true><<<gemm_grid, 512, 0, stream>>>(x, w1c, b1, supb, tpreb,
                                                   kN, 1024, kDIN, kDIN);
    agg_kernel<2><<<agg_grid, 256, 0, stream>>>(supb, tpreb, rowptr, e_src, e_w, h, hbf);

    // ---- 6 residual blocks x 2 convs
    for (int l = 0; l < 2 * kNBLK; ++l) {
        const unsigned short* A = (l & 1) ? tact : hbf;
        gemm_dual<false><<<gemm_grid, 512, 0, stream>>>(
            A, blkc + (long)l * 512 * 256, blkb + (long)l * 256,
            supb, tpreb, kN, 256, 256, 256);
        if (l & 1)
            agg_kernel<1><<<agg_grid, 256, 0, stream>>>(supb, tpreb, rowptr, e_src, e_w, h, hbf);
        else
            agg_kernel<0><<<agg_grid, 256, 0, stream>>>(supb, tpreb, rowptr, e_src, e_w, nullptr, tact);
    }

    // ---- final layer (fp32)
    final_layer_kernel<<<kN, 64, 0, stream>>>(h, W2, Wl2, b2, sup2, x_out);
    scatter3_kernel<<<(kE + 255) / 256, 256, 0, stream>>>(sup2, src, dst, ew, x_out);
}

// Round 7
// 1144.852 us; speedup vs baseline: 6.7142x; 1.1405x over previous
//
#include <hip/hip_runtime.h>

typedef __attribute__((ext_vector_type(8))) short short8;
typedef __attribute__((ext_vector_type(4))) float f32x4;

constexpr int kN = 50000;
constexpr int kE = 300000;
constexpr int kDIN = 963;
constexpr int kH = 256;
constexpr int kNBLK = 6;

__device__ inline unsigned short f2bf(float f) {
    unsigned u = __float_as_uint(f);
    u = u + 0x7FFFu + ((u >> 16) & 1u);   // RTNE
    return (unsigned short)(u >> 16);
}
__device__ inline float bf2f(unsigned short s) {
    return __uint_as_float(((unsigned)s) << 16);
}

__device__ inline void gload_lds16(const void* g, void* l) {
    __builtin_amdgcn_global_load_lds(
        (const __attribute__((address_space(1))) void*)g,
        (__attribute__((address_space(3))) void*)l, 16, 0, 0);
}

// ---------------------------------------------------------------------------
// Dual GEMM: [supb | tpreb] = A(MxK) @ Bt^T, Bt is [512][Kpad] bf16.
// Tile 128 rows x 256 cols, 8 waves (2 row x 4 col), 64x64 per wave,
// mfma_f32_16x16x32_bf16 swapped operands (lane&15 = output row).
// Grid: 782 linear blocks, bijective XCD-chunked swizzle (col fastest) so
// blocks sharing an A panel run on the same XCD.
// Epilogue: fp32 acc staged through LDS (32x256, XOR-swizzled), emitted as
// 256B-contiguous 128B-aligned bf16 stores.
// ---------------------------------------------------------------------------
template<bool ACVT>
__global__ __launch_bounds__(512) void gemm_dual(
    const void* __restrict__ Av, const unsigned short* __restrict__ Bt,
    const float* __restrict__ bias,
    unsigned short* __restrict__ supb, unsigned short* __restrict__ tpreb,
    int M, int Kpad, int Kvalid, int Astride)
{
    __shared__ __align__(16) char smem[49152];
    char* As = smem;             // 128 rows x 128 B (64 bf16 k)
    char* Bs = smem + 16384;     // 256 cols x 128 B

    const int tid = threadIdx.x;
    const int wid = tid >> 6;
    const int lane = tid & 63;
    const int wr = wid >> 2, wc = wid & 3;

    // bijective XCD-chunked tile decode (m204)
    const int nwg = gridDim.x;
    const int q = nwg >> 3, r = nwg & 7;
    const int xcd = blockIdx.x & 7, idx = blockIdx.x >> 3;
    const int t = (xcd < r ? xcd * (q + 1) : r * (q + 1) + (xcd - r) * q) + idx;
    const int r0 = (t >> 1) * 128;
    const int c0 = (t & 1) * 256;

    f32x4 acc[4][4];
#pragma unroll
    for (int i = 0; i < 4; ++i)
#pragma unroll
        for (int j = 0; j < 4; ++j) acc[i][j] = f32x4{0.f, 0.f, 0.f, 0.f};

    const int l_row = lane >> 3;      // 0..7
    const int l_c   = lane & 7;       // 16B chunk

    for (int k0 = 0; k0 < Kpad; k0 += 64) {
        // ---- stage B (weights): wave covers 32 tile-cols
#pragma unroll
        for (int p = 0; p < 4; ++p) {
            int row = wid * 32 + p * 8 + l_row;
            int csw = l_c ^ (row & 7);
            const unsigned short* g = Bt + (long)(c0 + row) * Kpad + k0 + csw * 8;
            gload_lds16(g, Bs + (wid * 32 + p * 8) * 128);
        }
        if (!ACVT) {
            // ---- stage A (bf16 activations): wave covers 16 rows
            const unsigned short* A = (const unsigned short*)Av;
#pragma unroll
            for (int p = 0; p < 2; ++p) {
                int row = wid * 16 + p * 8 + l_row;
                int grow = r0 + row; if (grow >= M) grow = M - 1;
                int csw = l_c ^ (row & 7);
                const unsigned short* g = A + (long)grow * Astride + k0 + csw * 8;
                gload_lds16(g, As + (wid * 16 + p * 8) * 128);
            }
        } else {
            // reg-stage fp32 A -> bf16 LDS (layer 1: x, K=963, Kpad=1024)
            const int row = tid >> 2;
            const int kq = tid & 3;
            int grow = r0 + row; if (grow >= M) grow = M - 1;
            const float* ar = (const float*)Av + (long)grow * Astride;
#pragma unroll
            for (int j = 0; j < 2; ++j) {
                int k16 = kq * 2 + j;
                short8 v;
#pragma unroll
                for (int ii = 0; ii < 8; ++ii) {
                    int k = k0 + k16 * 8 + ii;
                    float f = (k < Kvalid) ? ar[k] : 0.f;
                    v[ii] = (short)f2bf(f);
                }
                *(short8*)(As + row * 128 + ((k16 ^ (row & 7)) << 4)) = v;
            }
        }
        __syncthreads();

        // ---- compute: 2 x (8 ds_read_b128 + 16 MFMA)
#pragma unroll
        for (int kk = 0; kk < 2; ++kk) {
            short8 af[4], bfr[4];
            const int kg = kk * 4 + (lane >> 4);   // logical 16B chunk 0..7
#pragma unroll
            for (int nr = 0; nr < 4; ++nr) {
                int row = wr * 64 + nr * 16 + (lane & 15);
                af[nr] = *(const short8*)(As + row * 128 + ((kg ^ (row & 7)) << 4));
            }
#pragma unroll
            for (int mc = 0; mc < 4; ++mc) {
                int row = wc * 64 + mc * 16 + (lane & 15);
                bfr[mc] = *(const short8*)(Bs + row * 128 + ((kg ^ (row & 7)) << 4));
            }
#pragma unroll
            for (int mc = 0; mc < 4; ++mc)
#pragma unroll
                for (int nr = 0; nr < 4; ++nr)
                    acc[mc][nr] = __builtin_amdgcn_mfma_f32_16x16x32_bf16(
                        bfr[mc], af[nr], acc[mc][nr], 0, 0, 0);
        }
        __syncthreads();
    }

    // ---- epilogue: LDS-staged, full-line bf16 stores
    const bool isSup = (c0 == 0);
    unsigned short* outp = isSup ? supb : tpreb;
    float* eL = (float*)smem;                 // 32 x 256 fp32 = 32 KB
    const int wrow = wr * 16 + (lane & 15);   // 0..31
    const int qc = (lane >> 4) << 2;          // col quad base within 16

    for (int nr = 0; nr < 4; ++nr) {
        __syncthreads();
#pragma unroll
        for (int mc = 0; mc < 4; ++mc) {
            const int col = wc * 64 + mc * 16 + qc;
            f32x4 v = acc[mc][nr];
            if (!isSup) v += *(const f32x4*)(bias + col);
            const int c16 = col >> 2;                       // fp32 16B chunk
            *(f32x4*)(eL + wrow * 256 + ((c16 ^ wrow) << 2)) = v;
        }
        __syncthreads();
        const int tr = tid >> 4, j = tid & 15;
        const int gr = r0 + (tr >> 4) * 64 + nr * 16 + (tr & 15);
        if (gr < M) {
#pragma unroll
            for (int p = 0; p < 2; ++p) {
                const int u = j + 16 * p;                   // bf16 16B unit
                f32x4 lo = *(const f32x4*)(eL + tr * 256 + (((2 * u) ^ tr) << 2));
                f32x4 hi = *(const f32x4*)(eL + tr * 256 + (((2 * u + 1) ^ tr) << 2));
                uint4 pk;
                pk.x = (unsigned)f2bf(lo[0]) | ((unsigned)f2bf(lo[1]) << 16);
                pk.y = (unsigned)f2bf(lo[2]) | ((unsigned)f2bf(lo[3]) << 16);
                pk.z = (unsigned)f2bf(hi[0]) | ((unsigned)f2bf(hi[1]) << 16);
                pk.w = (unsigned)f2bf(hi[2]) | ((unsigned)f2bf(hi[3]) << 16);
                *(uint4*)(outp + (long)gr * 256 + u * 8) = pk;
            }
        }
    }
}

// ---------------------------------------------------------------------------
// CSR-gather aggregation, fused epilogue. One wave per node, lane owns 4 cols.
// 4-edge unrolled gather loop for memory-level parallelism.
// MODE 0: obf = bf16(relu(tpre + agg))                     (tact or layer-1 h)
// MODE 1: r = (hbf_in + relu(tpre + agg)) * 0.5; obf = bf16(r);
//         if WF32: h = r (fp32, final x_hidden)
// ---------------------------------------------------------------------------
template<int MODE, bool WF32>
__global__ __launch_bounds__(256) void agg_kernel(
    const unsigned short* __restrict__ supb, const unsigned short* __restrict__ tpreb,
    const int* __restrict__ rowptr, const int* __restrict__ e_src,
    const float* __restrict__ e_w,
    const unsigned short* __restrict__ hbf_in,
    float* __restrict__ h, unsigned short* __restrict__ obf)
{
    const int wid = threadIdx.x >> 6, lane = threadIdx.x & 63;
    const long node = (long)blockIdx.x * 4 + wid;
    if (node >= kN) return;
    const int c0 = lane << 2;

    ushort4 tv = *(const ushort4*)(tpreb + node * 256 + c0);
    f32x4 a = {bf2f(tv.x), bf2f(tv.y), bf2f(tv.z), bf2f(tv.w)};
    int b = rowptr[node];
    const int e = rowptr[node + 1];

    for (; b + 4 <= e; b += 4) {
        const int s0 = e_src[b],     s1 = e_src[b + 1];
        const int s2 = e_src[b + 2], s3 = e_src[b + 3];
        const float w0 = e_w[b],     w1 = e_w[b + 1];
        const float w2 = e_w[b + 2], w3 = e_w[b + 3];
        ushort4 v0 = *(const ushort4*)(supb + (long)s0 * 256 + c0);
        ushort4 v1 = *(const ushort4*)(supb + (long)s1 * 256 + c0);
        ushort4 v2 = *(const ushort4*)(supb + (long)s2 * 256 + c0);
        ushort4 v3 = *(const ushort4*)(supb + (long)s3 * 256 + c0);
        a[0] += w0 * bf2f(v0.x) + w1 * bf2f(v1.x) + w2 * bf2f(v2.x) + w3 * bf2f(v3.x);
        a[1] += w0 * bf2f(v0.y) + w1 * bf2f(v1.y) + w2 * bf2f(v2.y) + w3 * bf2f(v3.y);
        a[2] += w0 * bf2f(v0.z) + w1 * bf2f(v1.z) + w2 * bf2f(v2.z) + w3 * bf2f(v3.z);
        a[3] += w0 * bf2f(v0.w) + w1 * bf2f(v1.w) + w2 * bf2f(v2.w) + w3 * bf2f(v3.w);
    }
    for (; b < e; ++b) {
        const int s = e_src[b];
        const float w = e_w[b];
        ushort4 sv = *(const ushort4*)(supb + (long)s * 256 + c0);
        a[0] += w * bf2f(sv.x); a[1] += w * bf2f(sv.y);
        a[2] += w * bf2f(sv.z); a[3] += w * bf2f(sv.w);
    }
    a[0] = fmaxf(a[0], 0.f); a[1] = fmaxf(a[1], 0.f);
    a[2] = fmaxf(a[2], 0.f); a[3] = fmaxf(a[3], 0.f);

    f32x4 r = a;
    if (MODE == 1) {
        ushort4 hv = *(const ushort4*)(hbf_in + node * 256 + c0);
        r[0] = (bf2f(hv.x) + a[0]) * 0.5f;
        r[1] = (bf2f(hv.y) + a[1]) * 0.5f;
        r[2] = (bf2f(hv.z) + a[2]) * 0.5f;
        r[3] = (bf2f(hv.w) + a[3]) * 0.5f;
    }
    if (WF32)
        *(f32x4*)(h + node * 256 + c0) = r;

    uint2 pk;
    pk.x = (unsigned)f2bf(r[0]) | ((unsigned)f2bf(r[1]) << 16);
    pk.y = (unsigned)f2bf(r[2]) | ((unsigned)f2bf(r[3]) << 16);
    *(uint2*)(obf + node * 256 + c0) = pk;
}

// ---------------------------------------------------------------------------
// Weight conversion
// ---------------------------------------------------------------------------
__global__ __launch_bounds__(256) void cvt_w1_kernel(
    const float* __restrict__ W1, const float* __restrict__ Wl1,
    unsigned short* __restrict__ out)
{
    int idx = blockIdx.x * 256 + threadIdx.x;       // 512*1024
    if (idx >= 512 * 1024) return;
    int c = idx >> 10, k = idx & 1023;
    float v = 0.f;
    if (k < kDIN) v = (c < 256) ? W1[(long)k * 256 + c] : Wl1[(long)k * 256 + (c - 256)];
    out[idx] = f2bf(v);
}

__global__ __launch_bounds__(256) void cvt_blk_kernel(
    const float* __restrict__ blkW, const float* __restrict__ blkWl,
    unsigned short* __restrict__ out)
{
    int idx = blockIdx.x * 256 + threadIdx.x;       // 12*512*256
    if (idx >= 12 * 512 * 256) return;
    int l = idx >> 17;
    int rem = idx & 131071;
    int c = rem >> 8, k = rem & 255;
    float v = (c < 256) ? blkW[((long)l * 256 + k) * 256 + c]
                        : blkWl[((long)l * 256 + k) * 256 + (c - 256)];
    out[idx] = f2bf(v);
}

// ---------------------------------------------------------------------------
// CSR build: histogram -> hierarchical exclusive scan -> fill
// ---------------------------------------------------------------------------
__global__ __launch_bounds__(256) void hist_kernel(const int* __restrict__ dst,
                                                   int* __restrict__ counts)
{
    int e = blockIdx.x * 256 + threadIdx.x;
    if (e < kE) atomicAdd(&counts[dst[e]], 1);
}

__global__ __launch_bounds__(1024) void scan1_kernel(
    const int* __restrict__ counts, int* __restrict__ rowptr, int* __restrict__ bsum)
{
    __shared__ int s[1024];
    const int tid = threadIdx.x;
    const int g = blockIdx.x * 1024 + tid;
    const int v = (g < kN) ? counts[g] : 0;
    s[tid] = v; __syncthreads();
    for (int off = 1; off < 1024; off <<= 1) {
        int tv = (tid >= off) ? s[tid - off] : 0;
        __syncthreads();
        s[tid] += tv;
        __syncthreads();
    }
    if (g < kN) rowptr[g] = s[tid] - v;   // block-local exclusive
    if (tid == 1023) bsum[blockIdx.x] = s[1023];
}

__global__ __launch_bounds__(64) void scan2_kernel(int* __restrict__ bsum, int nb)
{
    __shared__ int s[64];
    const int tid = threadIdx.x;
    const int v = (tid < nb) ? bsum[tid] : 0;
    s[tid] = v; __syncthreads();
    for (int off = 1; off < 64; off <<= 1) {
        int tv = (tid >= off) ? s[tid - off] : 0;
        __syncthreads();
        s[tid] += tv;
        __syncthreads();
    }
    if (tid < nb) bsum[tid] = s[tid] - v;  // exclusive
}

__global__ __launch_bounds__(256) void scan3_kernel(
    int* __restrict__ rowptr, const int* __restrict__ bsum, int* __restrict__ cursor)
{
    int g = blockIdx.x * 256 + threadIdx.x;
    if (g < kN) {
        int r = rowptr[g] + bsum[g >> 10];
        rowptr[g] = r;
        cursor[g] = r;
    }
    if (g == 0) rowptr[kN] = kE;
}

__global__ __launch_bounds__(256) void fill_kernel(
    const int* __restrict__ src, const int* __restrict__ dst,
    const float* __restrict__ ew, int* __restrict__ cursor,
    int* __restrict__ e_src, float* __restrict__ e_w)
{
    int e = blockIdx.x * 256 + threadIdx.x;
    if (e >= kE) return;
    int d = dst[e];
    int pos = atomicAdd(&cursor[d], 1);
    e_src[pos] = src[e];
    e_w[pos] = ew[e];
}

// ---------------------------------------------------------------------------
// Final layer (DOUT=3): one wave per row, reads bf16 hidden
// ---------------------------------------------------------------------------
__global__ __launch_bounds__(64) void final_layer_kernel(
    const unsigned short* __restrict__ hbf, const float* __restrict__ W2,
    const float* __restrict__ Wl2, const float* __restrict__ b2,
    float* __restrict__ sup2, float* __restrict__ x_out)
{
    const int row = blockIdx.x;
    const int lane = threadIdx.x;
    const unsigned short* hr = hbf + (long)row * kH;
    float accW[3] = {0.f, 0.f, 0.f};
    float accL[3] = {0.f, 0.f, 0.f};
#pragma unroll
    for (int kb = 0; kb < kH / 64; ++kb) {
        int k = kb * 64 + lane;
        float v = bf2f(hr[k]);
#pragma unroll
        for (int c = 0; c < 3; ++c) {
            accW[c] = fmaf(v, W2[k * 3 + c], accW[c]);
            accL[c] = fmaf(v, Wl2[k * 3 + c], accL[c]);
        }
    }
#pragma unroll
    for (int off = 32; off > 0; off >>= 1) {
#pragma unroll
        for (int c = 0; c < 3; ++c) {
            accW[c] += __shfl_down(accW[c], off);
            accL[c] += __shfl_down(accL[c], off);
        }
    }
    if (lane == 0) {
#pragma unroll
        for (int c = 0; c < 3; ++c) {
            sup2[row * 3 + c] = accW[c];
            x_out[row * 3 + c] = accL[c] + b2[c];
        }
    }
}

__global__ __launch_bounds__(256) void scatter3_kernel(
    const float* __restrict__ sup2, const int* __restrict__ src,
    const int* __restrict__ dst, const float* __restrict__ ew,
    float* __restrict__ x_out)
{
    int e = blockIdx.x * 256 + threadIdx.x;
    if (e >= kE) return;
    int s = src[e];
    int d = dst[e];
    float w = ew[e];
#pragma unroll
    for (int c = 0; c < 3; ++c)
        atomicAdd(&x_out[(long)d * 3 + c], w * sup2[(long)s * 3 + c]);
}

// ---------------------------------------------------------------------------
extern "C" void kernel_launch(void* const* d_in, const int* in_sizes, int n_in,
                              void* d_out, int out_size, void* d_ws, size_t ws_size,
                              hipStream_t stream)
{
    const float* x    = (const float*)d_in[0];
    const int*   src  = (const int*)d_in[1];
    const int*   dst  = (const int*)d_in[2];
    const float* ew   = (const float*)d_in[3];
    const float* W1   = (const float*)d_in[4];
    const float* Wl1  = (const float*)d_in[5];
    const float* b1   = (const float*)d_in[6];
    const float* blkW  = (const float*)d_in[7];
    const float* blkWl = (const float*)d_in[8];
    const float* blkb  = (const float*)d_in[9];
    const float* W2   = (const float*)d_in[10];
    const float* Wl2  = (const float*)d_in[11];
    const float* b2   = (const float*)d_in[12];

    float* out   = (float*)d_out;
    float* x_out = out;                       // N*3
    float* h     = out + (long)kN * 3;        // N*H fp32 = x_hidden output

    // ---- workspace carve-up
    char* w = (char*)d_ws;
    size_t off = 0;
    auto carve = [&](size_t bytes) { char* p = w + off; off = (off + bytes + 255) & ~(size_t)255; return p; };
    unsigned short* supb  = (unsigned short*)carve(12800000UL * 2);
    unsigned short* tpreb = (unsigned short*)carve(12800000UL * 2);
    unsigned short* tact  = (unsigned short*)carve(12800000UL * 2);
    unsigned short* hbf   = (unsigned short*)carve(12800000UL * 2);
    unsigned short* w1c   = (unsigned short*)carve(512UL * 1024 * 2);
    unsigned short* blkc  = (unsigned short*)carve(12UL * 512 * 256 * 2);
    int*   e_src  = (int*)carve(kE * 4);
    float* e_w    = (float*)carve(kE * 4);
    int*   counts = (int*)carve(50176 * 4);
    int*   rowptr = (int*)carve(50176 * 4);
    int*   cursor = (int*)carve(50176 * 4);
    int*   bsum   = (int*)carve(64 * 4);
    float* sup2   = (float*)carve((long)kN * 3 * 4);

    // ---- CSR build
    hipMemsetAsync(counts, 0, 50176 * 4, stream);
    hist_kernel<<<(kE + 255) / 256, 256, 0, stream>>>(dst, counts);
    scan1_kernel<<<49, 1024, 0, stream>>>(counts, rowptr, bsum);
    scan2_kernel<<<1, 64, 0, stream>>>(bsum, 49);
    scan3_kernel<<<(kN + 255) / 256, 256, 0, stream>>>(rowptr, bsum, cursor);
    fill_kernel<<<(kE + 255) / 256, 256, 0, stream>>>(src, dst, ew, cursor, e_src, e_w);

    // ---- weight conversion (bf16, concatenated [W|Wl], transposed [col][k])
    cvt_w1_kernel<<<2048, 256, 0, stream>>>(W1, Wl1, w1c);
    cvt_blk_kernel<<<6144, 256, 0, stream>>>(blkW, blkWl, blkc);

    const int gemm_grid = 2 * ((kN + 127) / 128);   // 782 linear (col fastest)
    const int agg_grid = (kN + 3) / 4;

    // ---- Layer 1: hbf = bf16(relu(gconv(x))), K=963 (pad 1024)
    gemm_dual<true><<<gemm_grid, 512, 0, stream>>>(x, w1c, b1, supb, tpreb,
                                                   kN, 1024, kDIN, kDIN);
    agg_kernel<0, false><<<agg_grid, 256, 0, stream>>>(
        supb, tpreb, rowptr, e_src, e_w, nullptr, nullptr, hbf);

    // ---- 6 residual blocks x 2 convs (hidden carried as bf16 in hbf)
    for (int l = 0; l < 2 * kNBLK; ++l) {
        const unsigned short* A = (l & 1) ? tact : hbf;
        gemm_dual<false><<<gemm_grid, 512, 0, stream>>>(
            A, blkc + (long)l * 512 * 256, blkb + (long)l * 256,
            supb, tpreb, kN, 256, 256, 256);
        if (l & 1) {
            if (l == 2 * kNBLK - 1)   // last residual: also write fp32 x_hidden
                agg_kernel<1, true><<<agg_grid, 256, 0, stream>>>(
                    supb, tpreb, rowptr, e_src, e_w, hbf, h, hbf);
            else
                agg_kernel<1, false><<<agg_grid, 256, 0, stream>>>(
                    supb, tpreb, rowptr, e_src, e_w, hbf, nullptr, hbf);
        } else {
            agg_kernel<0, false><<<agg_grid, 256, 0, stream>>>(
                supb, tpreb, rowptr, e_src, e_w, nullptr, nullptr, tact);
        }
    }

    // ---- final layer
    final_layer_kernel<<<kN, 64, 0, stream>>>(hbf, W2, Wl2, b2, sup2, x_out);
    scatter3_kernel<<<(kE + 255) / 256, 256, 0, stream>>>(sup2, src, dst, ew, x_out);
}

// Round 9
// 1020.309 us; speedup vs baseline: 7.5338x; 1.1221x over previous
//
#include <hip/hip_runtime.h>

typedef __attribute__((ext_vector_type(8))) short short8;
typedef __attribute__((ext_vector_type(4))) float f32x4;

constexpr int kN = 50000;
constexpr int kE = 300000;
constexpr int kDIN = 963;
constexpr int kH = 256;
constexpr int kNBLK = 6;

__device__ inline unsigned short f2bf(float f) {
    unsigned u = __float_as_uint(f);
    u = u + 0x7FFFu + ((u >> 16) & 1u);   // RTNE
    return (unsigned short)(u >> 16);
}
__device__ inline float bf2f(unsigned short s) {
    return __uint_as_float(((unsigned)s) << 16);
}

__device__ inline void gload_lds16(const void* g, void* l) {
    __builtin_amdgcn_global_load_lds(
        (const __attribute__((address_space(1))) void*)g,
        (__attribute__((address_space(3))) void*)l, 16, 0, 0);
}

// ---------------------------------------------------------------------------
// Layer-1 dual GEMM (unchanged structure): [supb | tpreb] = x @ [W1|Wl1]^T
// fp32 A converted in-kernel, K=963 pad 1024. Tile 128x256, 8 waves.
// ---------------------------------------------------------------------------
__global__ __launch_bounds__(512) void gemm_l1(
    const float* __restrict__ Av, const unsigned short* __restrict__ Bt,
    const float* __restrict__ bias,
    unsigned short* __restrict__ supb, unsigned short* __restrict__ tpreb,
    int M, int Kpad, int Kvalid, int Astride)
{
    __shared__ __align__(16) char smem[49152];
    char* As = smem;             // 128 rows x 128 B
    char* Bs = smem + 16384;     // 256 cols x 128 B

    const int tid = threadIdx.x;
    const int wid = tid >> 6;
    const int lane = tid & 63;
    const int wr = wid >> 2, wc = wid & 3;

    const int nwg = gridDim.x;
    const int q = nwg >> 3, r = nwg & 7;
    const int xcd = blockIdx.x & 7, idx = blockIdx.x >> 3;
    const int t = (xcd < r ? xcd * (q + 1) : r * (q + 1) + (xcd - r) * q) + idx;
    const int r0 = (t >> 1) * 128;
    const int c0 = (t & 1) * 256;

    f32x4 acc[4][4];
#pragma unroll
    for (int i = 0; i < 4; ++i)
#pragma unroll
        for (int j = 0; j < 4; ++j) acc[i][j] = f32x4{0.f, 0.f, 0.f, 0.f};

    const int l_row = lane >> 3;
    const int l_c   = lane & 7;

    for (int k0 = 0; k0 < Kpad; k0 += 64) {
#pragma unroll
        for (int p = 0; p < 4; ++p) {
            int row = wid * 32 + p * 8 + l_row;
            int csw = l_c ^ (row & 7);
            const unsigned short* g = Bt + (long)(c0 + row) * Kpad + k0 + csw * 8;
            gload_lds16(g, Bs + (wid * 32 + p * 8) * 128);
        }
        {   // reg-stage fp32 A -> bf16 LDS
            const int row = tid >> 2;
            const int kq = tid & 3;
            int grow = r0 + row; if (grow >= M) grow = M - 1;
            const float* ar = Av + (long)grow * Astride;
#pragma unroll
            for (int j = 0; j < 2; ++j) {
                int k16 = kq * 2 + j;
                short8 v;
#pragma unroll
                for (int ii = 0; ii < 8; ++ii) {
                    int k = k0 + k16 * 8 + ii;
                    float f = (k < Kvalid) ? ar[k] : 0.f;
                    v[ii] = (short)f2bf(f);
                }
                *(short8*)(As + row * 128 + ((k16 ^ (row & 7)) << 4)) = v;
            }
        }
        __syncthreads();
#pragma unroll
        for (int kk = 0; kk < 2; ++kk) {
            short8 af[4], bfr[4];
            const int kg = kk * 4 + (lane >> 4);
#pragma unroll
            for (int nr = 0; nr < 4; ++nr) {
                int row = wr * 64 + nr * 16 + (lane & 15);
                af[nr] = *(const short8*)(As + row * 128 + ((kg ^ (row & 7)) << 4));
            }
#pragma unroll
            for (int mc = 0; mc < 4; ++mc) {
                int row = wc * 64 + mc * 16 + (lane & 15);
                bfr[mc] = *(const short8*)(Bs + row * 128 + ((kg ^ (row & 7)) << 4));
            }
#pragma unroll
            for (int mc = 0; mc < 4; ++mc)
#pragma unroll
                for (int nr = 0; nr < 4; ++nr)
                    acc[mc][nr] = __builtin_amdgcn_mfma_f32_16x16x32_bf16(
                        bfr[mc], af[nr], acc[mc][nr], 0, 0, 0);
        }
        __syncthreads();
    }

    const bool isSup = (c0 == 0);
    unsigned short* outp = isSup ? supb : tpreb;
    float* eL = (float*)smem;
    const int wrow = wr * 16 + (lane & 15);
    const int qc = (lane >> 4) << 2;

    for (int nr = 0; nr < 4; ++nr) {
        __syncthreads();
#pragma unroll
        for (int mc = 0; mc < 4; ++mc) {
            const int col = wc * 64 + mc * 16 + qc;
            f32x4 v = acc[mc][nr];
            if (!isSup) v += *(const f32x4*)(bias + col);
            const int c16 = col >> 2;
            *(f32x4*)(eL + wrow * 256 + ((c16 ^ wrow) << 2)) = v;
        }
        __syncthreads();
        const int tr = tid >> 4, j = tid & 15;
        const int gr = r0 + (tr >> 4) * 64 + nr * 16 + (tr & 15);
        if (gr < M) {
#pragma unroll
            for (int p = 0; p < 2; ++p) {
                const int u = j + 16 * p;
                f32x4 lo = *(const f32x4*)(eL + tr * 256 + (((2 * u) ^ tr) << 2));
                f32x4 hi = *(const f32x4*)(eL + tr * 256 + (((2 * u + 1) ^ tr) << 2));
                uint4 pk;
                pk.x = (unsigned)f2bf(lo[0]) | ((unsigned)f2bf(lo[1]) << 16);
                pk.y = (unsigned)f2bf(lo[2]) | ((unsigned)f2bf(lo[3]) << 16);
                pk.z = (unsigned)f2bf(hi[0]) | ((unsigned)f2bf(hi[1]) << 16);
                pk.w = (unsigned)f2bf(hi[2]) | ((unsigned)f2bf(hi[3]) << 16);
                *(uint4*)(outp + (long)gr * 256 + u * 8) = pk;
            }
        }
    }
}

// ---------------------------------------------------------------------------
// Block-layer fused GEMM: y = [act | xagg](Mx512) @ Bt^T + bias,
// Bt = [256 out-cols][512 k] bf16 (k<256: Wl cols, k>=256: W cols).
// RES 0: out = bf16(relu(y));  RES 1: out = bf16((hbf+relu(y))*0.5)
// RES 2: as 1, plus fp32 x_hidden write.
// Tile 128x256, grid 391 (one col-tile), XCD-chunked swizzle, K=512.
// ---------------------------------------------------------------------------
template<int RES>
__global__ __launch_bounds__(512) void gemm_blk(
    const unsigned short* __restrict__ act, const unsigned short* __restrict__ xagg,
    const unsigned short* __restrict__ Bt, const float* __restrict__ bias,
    const unsigned short* __restrict__ hbf_res,
    unsigned short* __restrict__ outbf, float* __restrict__ hf32)
{
    __shared__ __align__(16) char smem[49152];
    char* As = smem;             // 128 rows x 128 B
    char* Bs = smem + 16384;     // 256 out-cols x 128 B

    const int tid = threadIdx.x;
    const int wid = tid >> 6;
    const int lane = tid & 63;
    const int wr = wid >> 2, wc = wid & 3;

    const int nwg = gridDim.x;
    const int q = nwg >> 3, r = nwg & 7;
    const int xcd = blockIdx.x & 7, idx = blockIdx.x >> 3;
    const int t = (xcd < r ? xcd * (q + 1) : r * (q + 1) + (xcd - r) * q) + idx;
    const int r0 = t * 128;

    f32x4 acc[4][4];
#pragma unroll
    for (int i = 0; i < 4; ++i)
#pragma unroll
        for (int j = 0; j < 4; ++j) acc[i][j] = f32x4{0.f, 0.f, 0.f, 0.f};

    const int l_row = lane >> 3;
    const int l_c   = lane & 7;

    for (int k0 = 0; k0 < 512; k0 += 64) {
        // ---- stage B: wave covers 32 out-cols, stride 512
#pragma unroll
        for (int p = 0; p < 4; ++p) {
            int row = wid * 32 + p * 8 + l_row;
            int csw = l_c ^ (row & 7);
            const unsigned short* g = Bt + (long)row * 512 + k0 + csw * 8;
            gload_lds16(g, Bs + (wid * 32 + p * 8) * 128);
        }
        // ---- stage A: first 4 chunks from act, last 4 from xagg (stride 256)
        const unsigned short* Asrc = (k0 < 256) ? (act + k0) : (xagg + (k0 - 256));
#pragma unroll
        for (int p = 0; p < 2; ++p) {
            int row = wid * 16 + p * 8 + l_row;
            int grow = r0 + row; if (grow >= kN) grow = kN - 1;
            int csw = l_c ^ (row & 7);
            const unsigned short* g = Asrc + (long)grow * 256 + csw * 8;
            gload_lds16(g, As + (wid * 16 + p * 8) * 128);
        }
        __syncthreads();
#pragma unroll
        for (int kk = 0; kk < 2; ++kk) {
            short8 af[4], bfr[4];
            const int kg = kk * 4 + (lane >> 4);
#pragma unroll
            for (int nr = 0; nr < 4; ++nr) {
                int row = wr * 64 + nr * 16 + (lane & 15);
                af[nr] = *(const short8*)(As + row * 128 + ((kg ^ (row & 7)) << 4));
            }
#pragma unroll
            for (int mc = 0; mc < 4; ++mc) {
                int row = wc * 64 + mc * 16 + (lane & 15);
                bfr[mc] = *(const short8*)(Bs + row * 128 + ((kg ^ (row & 7)) << 4));
            }
#pragma unroll
            for (int mc = 0; mc < 4; ++mc)
#pragma unroll
                for (int nr = 0; nr < 4; ++nr)
                    acc[mc][nr] = __builtin_amdgcn_mfma_f32_16x16x32_bf16(
                        bfr[mc], af[nr], acc[mc][nr], 0, 0, 0);
        }
        __syncthreads();
    }

    // ---- epilogue: LDS-staged; fused bias + relu (+ residual) (+ fp32 h)
    float* eL = (float*)smem;                 // 32 x 256 fp32
    const int wrow = wr * 16 + (lane & 15);
    const int qc = (lane >> 4) << 2;

    for (int nr = 0; nr < 4; ++nr) {
        __syncthreads();
#pragma unroll
        for (int mc = 0; mc < 4; ++mc) {
            const int col = wc * 64 + mc * 16 + qc;
            f32x4 v = acc[mc][nr] + *(const f32x4*)(bias + col);
            const int c16 = col >> 2;
            *(f32x4*)(eL + wrow * 256 + ((c16 ^ wrow) << 2)) = v;
        }
        __syncthreads();
        const int tr = tid >> 4, j = tid & 15;
        const int gr = r0 + (tr >> 4) * 64 + nr * 16 + (tr & 15);
        if (gr < kN) {
#pragma unroll
            for (int p = 0; p < 2; ++p) {
                const int u = j + 16 * p;
                f32x4 lo = *(const f32x4*)(eL + tr * 256 + (((2 * u) ^ tr) << 2));
                f32x4 hi = *(const f32x4*)(eL + tr * 256 + (((2 * u + 1) ^ tr) << 2));
#pragma unroll
                for (int ii = 0; ii < 4; ++ii) {
                    lo[ii] = fmaxf(lo[ii], 0.f);
                    hi[ii] = fmaxf(hi[ii], 0.f);
                }
                if (RES >= 1) {
                    uint4 hv = *(const uint4*)(hbf_res + (long)gr * 256 + u * 8);
                    lo[0] = (bf2f((unsigned short)(hv.x & 0xFFFF)) + lo[0]) * 0.5f;
                    lo[1] = (bf2f((unsigned short)(hv.x >> 16))    + lo[1]) * 0.5f;
                    lo[2] = (bf2f((unsigned short)(hv.y & 0xFFFF)) + lo[2]) * 0.5f;
                    lo[3] = (bf2f((unsigned short)(hv.y >> 16))    + lo[3]) * 0.5f;
                    hi[0] = (bf2f((unsigned short)(hv.z & 0xFFFF)) + hi[0]) * 0.5f;
                    hi[1] = (bf2f((unsigned short)(hv.z >> 16))    + hi[1]) * 0.5f;
                    hi[2] = (bf2f((unsigned short)(hv.w & 0xFFFF)) + hi[2]) * 0.5f;
                    hi[3] = (bf2f((unsigned short)(hv.w >> 16))    + hi[3]) * 0.5f;
                }
                if (RES == 2) {
                    *(f32x4*)(hf32 + (long)gr * 256 + u * 8)     = lo;
                    *(f32x4*)(hf32 + (long)gr * 256 + u * 8 + 4) = hi;
                }
                uint4 pk;
                pk.x = (unsigned)f2bf(lo[0]) | ((unsigned)f2bf(lo[1]) << 16);
                pk.y = (unsigned)f2bf(lo[2]) | ((unsigned)f2bf(lo[3]) << 16);
                pk.z = (unsigned)f2bf(hi[0]) | ((unsigned)f2bf(hi[1]) << 16);
                pk.w = (unsigned)f2bf(hi[2]) | ((unsigned)f2bf(hi[3]) << 16);
                *(uint4*)(outbf + (long)gr * 256 + u * 8) = pk;
            }
        }
    }
}

// ---------------------------------------------------------------------------
// Layer-1 aggregation (old order): hbf = bf16(relu(tpreb + gather(supb)))
// ---------------------------------------------------------------------------
__global__ __launch_bounds__(256) void agg0_kernel(
    const unsigned short* __restrict__ supb, const unsigned short* __restrict__ tpreb,
    const int* __restrict__ rowptr, const int* __restrict__ e_src,
    const float* __restrict__ e_w, unsigned short* __restrict__ obf)
{
    const int wid = threadIdx.x >> 6, lane = threadIdx.x & 63;
    const long node = (long)blockIdx.x * 4 + wid;
    if (node >= kN) return;
    const int c0 = lane << 2;

    ushort4 tv = *(const ushort4*)(tpreb + node * 256 + c0);
    f32x4 a = {bf2f(tv.x), bf2f(tv.y), bf2f(tv.z), bf2f(tv.w)};
    int b = rowptr[node];
    const int e = rowptr[node + 1];
    for (; b + 4 <= e; b += 4) {
        const int s0 = e_src[b],     s1 = e_src[b + 1];
        const int s2 = e_src[b + 2], s3 = e_src[b + 3];
        const float w0 = e_w[b],     w1 = e_w[b + 1];
        const float w2 = e_w[b + 2], w3 = e_w[b + 3];
        ushort4 v0 = *(const ushort4*)(supb + (long)s0 * 256 + c0);
        ushort4 v1 = *(const ushort4*)(supb + (long)s1 * 256 + c0);
        ushort4 v2 = *(const ushort4*)(supb + (long)s2 * 256 + c0);
        ushort4 v3 = *(const ushort4*)(supb + (long)s3 * 256 + c0);
        a[0] += w0 * bf2f(v0.x) + w1 * bf2f(v1.x) + w2 * bf2f(v2.x) + w3 * bf2f(v3.x);
        a[1] += w0 * bf2f(v0.y) + w1 * bf2f(v1.y) + w2 * bf2f(v2.y) + w3 * bf2f(v3.y);
        a[2] += w0 * bf2f(v0.z) + w1 * bf2f(v1.z) + w2 * bf2f(v2.z) + w3 * bf2f(v3.z);
        a[3] += w0 * bf2f(v0.w) + w1 * bf2f(v1.w) + w2 * bf2f(v2.w) + w3 * bf2f(v3.w);
    }
    for (; b < e; ++b) {
        const int s = e_src[b];
        const float w = e_w[b];
        ushort4 sv = *(const ushort4*)(supb + (long)s * 256 + c0);
        a[0] += w * bf2f(sv.x); a[1] += w * bf2f(sv.y);
        a[2] += w * bf2f(sv.z); a[3] += w * bf2f(sv.w);
    }
    uint2 pk;
    pk.x = (unsigned)f2bf(fmaxf(a[0], 0.f)) | ((unsigned)f2bf(fmaxf(a[1], 0.f)) << 16);
    pk.y = (unsigned)f2bf(fmaxf(a[2], 0.f)) | ((unsigned)f2bf(fmaxf(a[3], 0.f)) << 16);
    *(uint2*)(obf + node * 256 + c0) = pk;
}

// ---------------------------------------------------------------------------
// Activation aggregation (linearity order): xagg = bf16(sum ew * act[src])
// ---------------------------------------------------------------------------
__global__ __launch_bounds__(256) void aggx_kernel(
    const unsigned short* __restrict__ act,
    const int* __restrict__ rowptr, const int* __restrict__ e_src,
    const float* __restrict__ e_w, unsigned short* __restrict__ xagg)
{
    const int wid = threadIdx.x >> 6, lane = threadIdx.x & 63;
    const long node = (long)blockIdx.x * 4 + wid;
    if (node >= kN) return;
    const int c0 = lane << 2;

    f32x4 a = {0.f, 0.f, 0.f, 0.f};
    int b = rowptr[node];
    const int e = rowptr[node + 1];
    for (; b + 4 <= e; b += 4) {
        const int s0 = e_src[b],     s1 = e_src[b + 1];
        const int s2 = e_src[b + 2], s3 = e_src[b + 3];
        const float w0 = e_w[b],     w1 = e_w[b + 1];
        const float w2 = e_w[b + 2], w3 = e_w[b + 3];
        ushort4 v0 = *(const ushort4*)(act + (long)s0 * 256 + c0);
        ushort4 v1 = *(const ushort4*)(act + (long)s1 * 256 + c0);
        ushort4 v2 = *(const ushort4*)(act + (long)s2 * 256 + c0);
        ushort4 v3 = *(const ushort4*)(act + (long)s3 * 256 + c0);
        a[0] += w0 * bf2f(v0.x) + w1 * bf2f(v1.x) + w2 * bf2f(v2.x) + w3 * bf2f(v3.x);
        a[1] += w0 * bf2f(v0.y) + w1 * bf2f(v1.y) + w2 * bf2f(v2.y) + w3 * bf2f(v3.y);
        a[2] += w0 * bf2f(v0.z) + w1 * bf2f(v1.z) + w2 * bf2f(v2.z) + w3 * bf2f(v3.z);
        a[3] += w0 * bf2f(v0.w) + w1 * bf2f(v1.w) + w2 * bf2f(v2.w) + w3 * bf2f(v3.w);
    }
    for (; b < e; ++b) {
        const int s = e_src[b];
        const float w = e_w[b];
        ushort4 sv = *(const ushort4*)(act + (long)s * 256 + c0);
        a[0] += w * bf2f(sv.x); a[1] += w * bf2f(sv.y);
        a[2] += w * bf2f(sv.z); a[3] += w * bf2f(sv.w);
    }
    uint2 pk;
    pk.x = (unsigned)f2bf(a[0]) | ((unsigned)f2bf(a[1]) << 16);
    pk.y = (unsigned)f2bf(a[2]) | ((unsigned)f2bf(a[3]) << 16);
    *(uint2*)(xagg + node * 256 + c0) = pk;
}

// ---------------------------------------------------------------------------
// Weight conversion
// ---------------------------------------------------------------------------
__global__ __launch_bounds__(256) void cvt_w1_kernel(
    const float* __restrict__ W1, const float* __restrict__ Wl1,
    unsigned short* __restrict__ out)
{
    int idx = blockIdx.x * 256 + threadIdx.x;       // 512*1024
    if (idx >= 512 * 1024) return;
    int c = idx >> 10, k = idx & 1023;
    float v = 0.f;
    if (k < kDIN) v = (c < 256) ? W1[(long)k * 256 + c] : Wl1[(long)k * 256 + (c - 256)];
    out[idx] = f2bf(v);
}

// blkc layout: [l][out-col c][k] ; k<256 -> Wl[k][c], k>=256 -> W[k-256][c]
__global__ __launch_bounds__(256) void cvt_blk_kernel(
    const float* __restrict__ blkW, const float* __restrict__ blkWl,
    unsigned short* __restrict__ out)
{
    int idx = blockIdx.x * 256 + threadIdx.x;       // 12*256*512
    if (idx >= 12 * 256 * 512) return;
    int l = idx >> 17;
    int rem = idx & 131071;
    int c = rem >> 9, k = rem & 511;
    float v = (k < 256) ? blkWl[((long)l * 256 + k) * 256 + c]
                        : blkW[((long)l * 256 + (k - 256)) * 256 + c];
    out[idx] = f2bf(v);
}

// ---------------------------------------------------------------------------
// CSR build: histogram -> hierarchical exclusive scan -> fill
// ---------------------------------------------------------------------------
__global__ __launch_bounds__(256) void hist_kernel(const int* __restrict__ dst,
                                                   int* __restrict__ counts)
{
    int e = blockIdx.x * 256 + threadIdx.x;
    if (e < kE) atomicAdd(&counts[dst[e]], 1);
}

__global__ __launch_bounds__(1024) void scan1_kernel(
    const int* __restrict__ counts, int* __restrict__ rowptr, int* __restrict__ bsum)
{
    __shared__ int s[1024];
    const int tid = threadIdx.x;
    const int g = blockIdx.x * 1024 + tid;
    const int v = (g < kN) ? counts[g] : 0;
    s[tid] = v; __syncthreads();
    for (int off = 1; off < 1024; off <<= 1) {
        int tv = (tid >= off) ? s[tid - off] : 0;
        __syncthreads();
        s[tid] += tv;
        __syncthreads();
    }
    if (g < kN) rowptr[g] = s[tid] - v;
    if (tid == 1023) bsum[blockIdx.x] = s[1023];
}

__global__ __launch_bounds__(64) void scan2_kernel(int* __restrict__ bsum, int nb)
{
    __shared__ int s[64];
    const int tid = threadIdx.x;
    const int v = (tid < nb) ? bsum[tid] : 0;
    s[tid] = v; __syncthreads();
    for (int off = 1; off < 64; off <<= 1) {
        int tv = (tid >= off) ? s[tid - off] : 0;
        __syncthreads();
        s[tid] += tv;
        __syncthreads();
    }
    if (tid < nb) bsum[tid] = s[tid] - v;
}

__global__ __launch_bounds__(256) void scan3_kernel(
    int* __restrict__ rowptr, const int* __restrict__ bsum, int* __restrict__ cursor)
{
    int g = blockIdx.x * 256 + threadIdx.x;
    if (g < kN) {
        int r = rowptr[g] + bsum[g >> 10];
        rowptr[g] = r;
        cursor[g] = r;
    }
    if (g == 0) rowptr[kN] = kE;
}

__global__ __launch_bounds__(256) void fill_kernel(
    const int* __restrict__ src, const int* __restrict__ dst,
    const float* __restrict__ ew, int* __restrict__ cursor,
    int* __restrict__ e_src, float* __restrict__ e_w)
{
    int e = blockIdx.x * 256 + threadIdx.x;
    if (e >= kE) return;
    int d = dst[e];
    int pos = atomicAdd(&cursor[d], 1);
    e_src[pos] = src[e];
    e_w[pos] = ew[e];
}

// ---------------------------------------------------------------------------
// Final layer (DOUT=3): one wave per row, reads bf16 hidden
// ---------------------------------------------------------------------------
__global__ __launch_bounds__(64) void final_layer_kernel(
    const unsigned short* __restrict__ hbf, const float* __restrict__ W2,
    const float* __restrict__ Wl2, const float* __restrict__ b2,
    float* __restrict__ sup2, float* __restrict__ x_out)
{
    const int row = blockIdx.x;
    const int lane = threadIdx.x;
    const unsigned short* hr = hbf + (long)row * kH;
    float accW[3] = {0.f, 0.f, 0.f};
    float accL[3] = {0.f, 0.f, 0.f};
#pragma unroll
    for (int kb = 0; kb < kH / 64; ++kb) {
        int k = kb * 64 + lane;
        float v = bf2f(hr[k]);
#pragma unroll
        for (int c = 0; c < 3; ++c) {
            accW[c] = fmaf(v, W2[k * 3 + c], accW[c]);
            accL[c] = fmaf(v, Wl2[k * 3 + c], accL[c]);
        }
    }
#pragma unroll
    for (int off = 32; off > 0; off >>= 1) {
#pragma unroll
        for (int c = 0; c < 3; ++c) {
            accW[c] += __shfl_down(accW[c], off);
            accL[c] += __shfl_down(accL[c], off);
        }
    }
    if (lane == 0) {
#pragma unroll
        for (int c = 0; c < 3; ++c) {
            sup2[row * 3 + c] = accW[c];
            x_out[row * 3 + c] = accL[c] + b2[c];
        }
    }
}

__global__ __launch_bounds__(256) void scatter3_kernel(
    const float* __restrict__ sup2, const int* __restrict__ src,
    const int* __restrict__ dst, const float* __restrict__ ew,
    float* __restrict__ x_out)
{
    int e = blockIdx.x * 256 + threadIdx.x;
    if (e >= kE) return;
    int s = src[e];
    int d = dst[e];
    float w = ew[e];
#pragma unroll
    for (int c = 0; c < 3; ++c)
        atomicAdd(&x_out[(long)d * 3 + c], w * sup2[(long)s * 3 + c]);
}

// ---------------------------------------------------------------------------
extern "C" void kernel_launch(void* const* d_in, const int* in_sizes, int n_in,
                              void* d_out, int out_size, void* d_ws, size_t ws_size,
                              hipStream_t stream)
{
    const float* x    = (const float*)d_in[0];
    const int*   src  = (const int*)d_in[1];
    const int*   dst  = (const int*)d_in[2];
    const float* ew   = (const float*)d_in[3];
    const float* W1   = (const float*)d_in[4];
    const float* Wl1  = (const float*)d_in[5];
    const float* b1   = (const float*)d_in[6];
    const float* blkW  = (const float*)d_in[7];
    const float* blkWl = (const float*)d_in[8];
    const float* blkb  = (const float*)d_in[9];
    const float* W2   = (const float*)d_in[10];
    const float* Wl2  = (const float*)d_in[11];
    const float* b2   = (const float*)d_in[12];

    float* out   = (float*)d_out;
    float* x_out = out;                       // N*3
    float* h     = out + (long)kN * 3;        // N*H fp32 = x_hidden output

    // ---- workspace carve-up
    char* w = (char*)d_ws;
    size_t off = 0;
    auto carve = [&](size_t bytes) { char* p = w + off; off = (off + bytes + 255) & ~(size_t)255; return p; };
    unsigned short* supb  = (unsigned short*)carve(12800000UL * 2);
    unsigned short* tpreb = (unsigned short*)carve(12800000UL * 2);  // layer-1 only
    unsigned short* tact  = (unsigned short*)carve(12800000UL * 2);
    unsigned short* hbf   = (unsigned short*)carve(12800000UL * 2);
    unsigned short* w1c   = (unsigned short*)carve(512UL * 1024 * 2);
    unsigned short* blkc  = (unsigned short*)carve(12UL * 256 * 512 * 2);
    int*   e_src  = (int*)carve(kE * 4);
    float* e_w    = (float*)carve(kE * 4);
    int*   counts = (int*)carve(50176 * 4);
    int*   rowptr = (int*)carve(50176 * 4);
    int*   cursor = (int*)carve(50176 * 4);
    int*   bsum   = (int*)carve(64 * 4);
    float* sup2   = (float*)carve((long)kN * 3 * 4);
    unsigned short* xagg = tpreb;             // alias: tpreb dead after agg0

    // ---- CSR build
    hipMemsetAsync(counts, 0, 50176 * 4, stream);
    hist_kernel<<<(kE + 255) / 256, 256, 0, stream>>>(dst, counts);
    scan1_kernel<<<49, 1024, 0, stream>>>(counts, rowptr, bsum);
    scan2_kernel<<<1, 64, 0, stream>>>(bsum, 49);
    scan3_kernel<<<(kN + 255) / 256, 256, 0, stream>>>(rowptr, bsum, cursor);
    fill_kernel<<<(kE + 255) / 256, 256, 0, stream>>>(src, dst, ew, cursor, e_src, e_w);

    // ---- weight conversion
    cvt_w1_kernel<<<2048, 256, 0, stream>>>(W1, Wl1, w1c);
    cvt_blk_kernel<<<6144, 256, 0, stream>>>(blkW, blkWl, blkc);

    const int l1_grid  = 2 * ((kN + 127) / 128);   // 782
    const int blk_grid = (kN + 127) / 128;         // 391
    const int agg_grid = (kN + 3) / 4;

    // ---- Layer 1 (old order): hbf = bf16(relu(gconv(x)))
    gemm_l1<<<l1_grid, 512, 0, stream>>>(x, w1c, b1, supb, tpreb,
                                         kN, 1024, kDIN, kDIN);
    agg0_kernel<<<agg_grid, 256, 0, stream>>>(supb, tpreb, rowptr, e_src, e_w, hbf);

    // ---- 12 block convs (linearity order: agg-first, K=512 fused GEMM)
    for (int l = 0; l < 2 * kNBLK; ++l) {
        const unsigned short* act_in = (l & 1) ? tact : hbf;
        unsigned short* act_out      = (l & 1) ? hbf : tact;
        aggx_kernel<<<agg_grid, 256, 0, stream>>>(act_in, rowptr, e_src, e_w, xagg);
        const unsigned short* B = blkc + (long)l * 256 * 512;
        const float* bb = blkb + (long)l * 256;
        if (l & 1) {
            if (l == 2 * kNBLK - 1)
                gemm_blk<2><<<blk_grid, 512, 0, stream>>>(act_in, xagg, B, bb, hbf, act_out, h);
            else
                gemm_blk<1><<<blk_grid, 512, 0, stream>>>(act_in, xagg, B, bb, hbf, act_out, nullptr);
        } else {
            gemm_blk<0><<<blk_grid, 512, 0, stream>>>(act_in, xagg, B, bb, nullptr, act_out, nullptr);
        }
    }

    // ---- final layer
    final_layer_kernel<<<kN, 64, 0, stream>>>(hbf, W2, Wl2, b2, sup2, x_out);
    scatter3_kernel<<<(kE + 255) / 256, 256, 0, stream>>>(sup2, src, dst, ew, x_out);
}

// Round 10
// 979.448 us; speedup vs baseline: 7.8481x; 1.0417x over previous
//
#include <hip/hip_runtime.h>

typedef __attribute__((ext_vector_type(8))) short short8;
typedef __attribute__((ext_vector_type(4))) float f32x4;
typedef __attribute__((ext_vector_type(4), aligned(4))) float f32x4u;  // 4B-aligned loads

constexpr int kN = 50000;
constexpr int kE = 300000;
constexpr int kDIN = 963;
constexpr int kH = 256;
constexpr int kNBLK = 6;

__device__ inline unsigned short f2bf(float f) {
    unsigned u = __float_as_uint(f);
    u = u + 0x7FFFu + ((u >> 16) & 1u);   // RTNE
    return (unsigned short)(u >> 16);
}
__device__ inline float bf2f(unsigned short s) {
    return __uint_as_float(((unsigned)s) << 16);
}

__device__ inline void gload_lds16(const void* g, void* l) {
    __builtin_amdgcn_global_load_lds(
        (const __attribute__((address_space(1))) void*)g,
        (__attribute__((address_space(3))) void*)l, 16, 0, 0);
}

// ---------------------------------------------------------------------------
// Layer-1 dual GEMM: [supb | tpreb] = x @ [W1|Wl1]^T
// fp32 A converted in-kernel (vectorized chunk loads), K=963 pad 1024.
// Tile 128x256, 8 waves (2x4), grid 782 (2 col-tiles x 391), XCD swizzle.
// ---------------------------------------------------------------------------
__global__ __launch_bounds__(512) void gemm_l1(
    const float* __restrict__ Av, const unsigned short* __restrict__ Bt,
    const float* __restrict__ bias,
    unsigned short* __restrict__ supb, unsigned short* __restrict__ tpreb,
    int M, int Kpad, int Kvalid, int Astride)
{
    __shared__ __align__(16) char smem[49152];
    char* As = smem;             // 128 rows x 128 B
    char* Bs = smem + 16384;     // 256 cols x 128 B

    const int tid = threadIdx.x;
    const int wid = tid >> 6;
    const int lane = tid & 63;
    const int wr = wid >> 2, wc = wid & 3;

    const int nwg = gridDim.x;
    const int q = nwg >> 3, r = nwg & 7;
    const int xcd = blockIdx.x & 7, idx = blockIdx.x >> 3;
    const int t = (xcd < r ? xcd * (q + 1) : r * (q + 1) + (xcd - r) * q) + idx;
    const int r0 = (t >> 1) * 128;
    const int c0 = (t & 1) * 256;

    f32x4 acc[4][4];
#pragma unroll
    for (int i = 0; i < 4; ++i)
#pragma unroll
        for (int j = 0; j < 4; ++j) acc[i][j] = f32x4{0.f, 0.f, 0.f, 0.f};

    const int l_row = lane >> 3;
    const int l_c   = lane & 7;

    for (int k0 = 0; k0 < Kpad; k0 += 64) {
#pragma unroll
        for (int p = 0; p < 4; ++p) {
            int row = wid * 32 + p * 8 + l_row;
            int csw = l_c ^ (row & 7);
            const unsigned short* g = Bt + (long)(c0 + row) * Kpad + k0 + csw * 8;
            gload_lds16(g, Bs + (wid * 32 + p * 8) * 128);
        }
        {   // reg-stage fp32 A -> bf16 LDS, vectorized where fully in-bounds
            const int row = tid >> 2;
            const int kq = tid & 3;
            int grow = r0 + row; if (grow >= M) grow = M - 1;
            const float* ar = Av + (long)grow * Astride;
#pragma unroll
            for (int j = 0; j < 2; ++j) {
                int k16 = kq * 2 + j;
                int kb = k0 + k16 * 8;
                short8 v;
                if (kb + 8 <= Kvalid) {
                    f32x4u f0 = *(const f32x4u*)(ar + kb);
                    f32x4u f1 = *(const f32x4u*)(ar + kb + 4);
#pragma unroll
                    for (int ii = 0; ii < 4; ++ii) {
                        v[ii]     = (short)f2bf(f0[ii]);
                        v[ii + 4] = (short)f2bf(f1[ii]);
                    }
                } else {
#pragma unroll
                    for (int ii = 0; ii < 8; ++ii) {
                        int k = kb + ii;
                        float f = (k < Kvalid) ? ar[k] : 0.f;
                        v[ii] = (short)f2bf(f);
                    }
                }
                *(short8*)(As + row * 128 + ((k16 ^ (row & 7)) << 4)) = v;
            }
        }
        __syncthreads();
#pragma unroll
        for (int kk = 0; kk < 2; ++kk) {
            short8 af[4], bfr[4];
            const int kg = kk * 4 + (lane >> 4);
#pragma unroll
            for (int nr = 0; nr < 4; ++nr) {
                int row = wr * 64 + nr * 16 + (lane & 15);
                af[nr] = *(const short8*)(As + row * 128 + ((kg ^ (row & 7)) << 4));
            }
#pragma unroll
            for (int mc = 0; mc < 4; ++mc) {
                int row = wc * 64 + mc * 16 + (lane & 15);
                bfr[mc] = *(const short8*)(Bs + row * 128 + ((kg ^ (row & 7)) << 4));
            }
#pragma unroll
            for (int mc = 0; mc < 4; ++mc)
#pragma unroll
                for (int nr = 0; nr < 4; ++nr)
                    acc[mc][nr] = __builtin_amdgcn_mfma_f32_16x16x32_bf16(
                        bfr[mc], af[nr], acc[mc][nr], 0, 0, 0);
        }
        __syncthreads();
    }

    const bool isSup = (c0 == 0);
    unsigned short* outp = isSup ? supb : tpreb;
    float* eL = (float*)smem;
    const int wrow = wr * 16 + (lane & 15);
    const int qc = (lane >> 4) << 2;

    for (int nr = 0; nr < 4; ++nr) {
        __syncthreads();
#pragma unroll
        for (int mc = 0; mc < 4; ++mc) {
            const int col = wc * 64 + mc * 16 + qc;
            f32x4 v = acc[mc][nr];
            if (!isSup) v += *(const f32x4*)(bias + col);
            const int c16 = col >> 2;
            *(f32x4*)(eL + wrow * 256 + ((c16 ^ wrow) << 2)) = v;
        }
        __syncthreads();
        const int tr = tid >> 4, j = tid & 15;
        const int gr = r0 + (tr >> 4) * 64 + nr * 16 + (tr & 15);
        if (gr < M) {
#pragma unroll
            for (int p = 0; p < 2; ++p) {
                const int u = j + 16 * p;
                f32x4 lo = *(const f32x4*)(eL + tr * 256 + (((2 * u) ^ tr) << 2));
                f32x4 hi = *(const f32x4*)(eL + tr * 256 + (((2 * u + 1) ^ tr) << 2));
                uint4 pk;
                pk.x = (unsigned)f2bf(lo[0]) | ((unsigned)f2bf(lo[1]) << 16);
                pk.y = (unsigned)f2bf(lo[2]) | ((unsigned)f2bf(lo[3]) << 16);
                pk.z = (unsigned)f2bf(hi[0]) | ((unsigned)f2bf(hi[1]) << 16);
                pk.w = (unsigned)f2bf(hi[2]) | ((unsigned)f2bf(hi[3]) << 16);
                *(uint4*)(outp + (long)gr * 256 + u * 8) = pk;
            }
        }
    }
}

// ---------------------------------------------------------------------------
// Block-layer fused GEMM: y = [act | xagg](Mx512) @ Bt^T + bias,
// Bt = [256 out-cols][512 k] bf16 (k<256: Wl cols, k>=256: W cols).
// RES 0: out = bf16(relu(y));  RES 1: out = bf16((hbf+relu(y))*0.5)
// RES 2: as 1, plus fp32 x_hidden write.
// Tile 128x128, 4 waves (2x2), grid 782 (2 col x 391 row) -> 3.05 blocks/CU
// balanced; LDS 32 KB -> 5 blocks/CU resident. XCD-chunked swizzle.
// ---------------------------------------------------------------------------
template<int RES>
__global__ __launch_bounds__(256) void gemm_blk(
    const unsigned short* __restrict__ act, const unsigned short* __restrict__ xagg,
    const unsigned short* __restrict__ Bt, const float* __restrict__ bias,
    const unsigned short* __restrict__ hbf_res,
    unsigned short* __restrict__ outbf, float* __restrict__ hf32)
{
    __shared__ __align__(16) char smem[32768];
    char* As = smem;             // 128 rows x 128 B
    char* Bs = smem + 16384;     // 128 out-cols x 128 B

    const int tid = threadIdx.x;
    const int wid = tid >> 6;      // 0..3
    const int lane = tid & 63;
    const int wr = wid >> 1, wc = wid & 1;

    const int nwg = gridDim.x;
    const int q = nwg >> 3, r = nwg & 7;
    const int xcd = blockIdx.x & 7, idx = blockIdx.x >> 3;
    const int t = (xcd < r ? xcd * (q + 1) : r * (q + 1) + (xcd - r) * q) + idx;
    const int r0 = (t >> 1) * 128;
    const int c0 = (t & 1) * 128;

    f32x4 acc[4][4];
#pragma unroll
    for (int i = 0; i < 4; ++i)
#pragma unroll
        for (int j = 0; j < 4; ++j) acc[i][j] = f32x4{0.f, 0.f, 0.f, 0.f};

    const int l_row = lane >> 3;
    const int l_c   = lane & 7;

    for (int k0 = 0; k0 < 512; k0 += 64) {
        // ---- stage B: 128 out-cols, 4 waves x 32
#pragma unroll
        for (int p = 0; p < 4; ++p) {
            int row = wid * 32 + p * 8 + l_row;
            int csw = l_c ^ (row & 7);
            const unsigned short* g = Bt + (long)(c0 + row) * 512 + k0 + csw * 8;
            gload_lds16(g, Bs + (wid * 32 + p * 8) * 128);
        }
        // ---- stage A: 128 rows, first half from act, second from xagg
        const unsigned short* Asrc = (k0 < 256) ? (act + k0) : (xagg + (k0 - 256));
#pragma unroll
        for (int p = 0; p < 4; ++p) {
            int row = wid * 32 + p * 8 + l_row;
            int grow = r0 + row; if (grow >= kN) grow = kN - 1;
            int csw = l_c ^ (row & 7);
            const unsigned short* g = Asrc + (long)grow * 256 + csw * 8;
            gload_lds16(g, As + (wid * 32 + p * 8) * 128);
        }
        __syncthreads();
#pragma unroll
        for (int kk = 0; kk < 2; ++kk) {
            short8 af[4], bfr[4];
            const int kg = kk * 4 + (lane >> 4);
#pragma unroll
            for (int nr = 0; nr < 4; ++nr) {
                int row = wr * 64 + nr * 16 + (lane & 15);
                af[nr] = *(const short8*)(As + row * 128 + ((kg ^ (row & 7)) << 4));
            }
#pragma unroll
            for (int mc = 0; mc < 4; ++mc) {
                int row = wc * 64 + mc * 16 + (lane & 15);
                bfr[mc] = *(const short8*)(Bs + row * 128 + ((kg ^ (row & 7)) << 4));
            }
#pragma unroll
            for (int mc = 0; mc < 4; ++mc)
#pragma unroll
                for (int nr = 0; nr < 4; ++nr)
                    acc[mc][nr] = __builtin_amdgcn_mfma_f32_16x16x32_bf16(
                        bfr[mc], af[nr], acc[mc][nr], 0, 0, 0);
        }
        __syncthreads();
    }

    // ---- epilogue: LDS-staged; fused bias + relu (+ residual) (+ fp32 h)
    float* eL = (float*)smem;                 // 32 x 128 fp32 = 16 KB
    const int wrow = wr * 16 + (lane & 15);   // 0..31
    const int qc = (lane >> 4) << 2;

    for (int nr = 0; nr < 4; ++nr) {
        __syncthreads();
#pragma unroll
        for (int mc = 0; mc < 4; ++mc) {
            const int col = wc * 64 + mc * 16 + qc;   // 0..127
            f32x4 v = acc[mc][nr] + *(const f32x4*)(bias + c0 + col);
            const int c16 = col >> 2;                 // 0..31
            *(f32x4*)(eL + wrow * 128 + ((c16 ^ wrow) << 2)) = v;
        }
        __syncthreads();
        const int tr = tid >> 3, j = tid & 7;         // 32 rows x 8 threads
        const int gr = r0 + (tr >> 4) * 64 + nr * 16 + (tr & 15);
        if (gr < kN) {
#pragma unroll
            for (int p = 0; p < 2; ++p) {
                const int u = j + 8 * p;              // 16B bf16 unit, 0..15
                f32x4 lo = *(const f32x4*)(eL + tr * 128 + (((2 * u) ^ tr) << 2));
                f32x4 hi = *(const f32x4*)(eL + tr * 128 + (((2 * u + 1) ^ tr) << 2));
#pragma unroll
                for (int ii = 0; ii < 4; ++ii) {
                    lo[ii] = fmaxf(lo[ii], 0.f);
                    hi[ii] = fmaxf(hi[ii], 0.f);
                }
                const long gcol = (long)gr * 256 + c0 + u * 8;
                if (RES >= 1) {
                    uint4 hv = *(const uint4*)(hbf_res + gcol);
                    lo[0] = (bf2f((unsigned short)(hv.x & 0xFFFF)) + lo[0]) * 0.5f;
                    lo[1] = (bf2f((unsigned short)(hv.x >> 16))    + lo[1]) * 0.5f;
                    lo[2] = (bf2f((unsigned short)(hv.y & 0xFFFF)) + lo[2]) * 0.5f;
                    lo[3] = (bf2f((unsigned short)(hv.y >> 16))    + lo[3]) * 0.5f;
                    hi[0] = (bf2f((unsigned short)(hv.z & 0xFFFF)) + hi[0]) * 0.5f;
                    hi[1] = (bf2f((unsigned short)(hv.z >> 16))    + hi[1]) * 0.5f;
                    hi[2] = (bf2f((unsigned short)(hv.w & 0xFFFF)) + hi[2]) * 0.5f;
                    hi[3] = (bf2f((unsigned short)(hv.w >> 16))    + hi[3]) * 0.5f;
                }
                if (RES == 2) {
                    *(f32x4*)(hf32 + gcol)     = lo;
                    *(f32x4*)(hf32 + gcol + 4) = hi;
                }
                uint4 pk;
                pk.x = (unsigned)f2bf(lo[0]) | ((unsigned)f2bf(lo[1]) << 16);
                pk.y = (unsigned)f2bf(lo[2]) | ((unsigned)f2bf(lo[3]) << 16);
                pk.z = (unsigned)f2bf(hi[0]) | ((unsigned)f2bf(hi[1]) << 16);
                pk.w = (unsigned)f2bf(hi[2]) | ((unsigned)f2bf(hi[3]) << 16);
                *(uint4*)(outbf + gcol) = pk;
            }
        }
    }
}

// ---------------------------------------------------------------------------
// Layer-1 aggregation (old order): hbf = bf16(relu(tpreb + gather(supb)))
// ---------------------------------------------------------------------------
__global__ __launch_bounds__(256) void agg0_kernel(
    const unsigned short* __restrict__ supb, const unsigned short* __restrict__ tpreb,
    const int* __restrict__ rowptr, const int* __restrict__ e_src,
    const float* __restrict__ e_w, unsigned short* __restrict__ obf)
{
    const int wid = threadIdx.x >> 6, lane = threadIdx.x & 63;
    const long node = (long)blockIdx.x * 4 + wid;
    if (node >= kN) return;
    const int c0 = lane << 2;

    ushort4 tv = *(const ushort4*)(tpreb + node * 256 + c0);
    f32x4 a = {bf2f(tv.x), bf2f(tv.y), bf2f(tv.z), bf2f(tv.w)};
    int b = rowptr[node];
    const int e = rowptr[node + 1];
    for (; b + 4 <= e; b += 4) {
        const int s0 = e_src[b],     s1 = e_src[b + 1];
        const int s2 = e_src[b + 2], s3 = e_src[b + 3];
        const float w0 = e_w[b],     w1 = e_w[b + 1];
        const float w2 = e_w[b + 2], w3 = e_w[b + 3];
        ushort4 v0 = *(const ushort4*)(supb + (long)s0 * 256 + c0);
        ushort4 v1 = *(const ushort4*)(supb + (long)s1 * 256 + c0);
        ushort4 v2 = *(const ushort4*)(supb + (long)s2 * 256 + c0);
        ushort4 v3 = *(const ushort4*)(supb + (long)s3 * 256 + c0);
        a[0] += w0 * bf2f(v0.x) + w1 * bf2f(v1.x) + w2 * bf2f(v2.x) + w3 * bf2f(v3.x);
        a[1] += w0 * bf2f(v0.y) + w1 * bf2f(v1.y) + w2 * bf2f(v2.y) + w3 * bf2f(v3.y);
        a[2] += w0 * bf2f(v0.z) + w1 * bf2f(v1.z) + w2 * bf2f(v2.z) + w3 * bf2f(v3.z);
        a[3] += w0 * bf2f(v0.w) + w1 * bf2f(v1.w) + w2 * bf2f(v2.w) + w3 * bf2f(v3.w);
    }
    for (; b < e; ++b) {
        const int s = e_src[b];
        const float w = e_w[b];
        ushort4 sv = *(const ushort4*)(supb + (long)s * 256 + c0);
        a[0] += w * bf2f(sv.x); a[1] += w * bf2f(sv.y);
        a[2] += w * bf2f(sv.z); a[3] += w * bf2f(sv.w);
    }
    uint2 pk;
    pk.x = (unsigned)f2bf(fmaxf(a[0], 0.f)) | ((unsigned)f2bf(fmaxf(a[1], 0.f)) << 16);
    pk.y = (unsigned)f2bf(fmaxf(a[2], 0.f)) | ((unsigned)f2bf(fmaxf(a[3], 0.f)) << 16);
    *(uint2*)(obf + node * 256 + c0) = pk;
}

// ---------------------------------------------------------------------------
// Activation aggregation (linearity order): xagg = bf16(sum ew * act[src])
// ---------------------------------------------------------------------------
__global__ __launch_bounds__(256) void aggx_kernel(
    const unsigned short* __restrict__ act,
    const int* __restrict__ rowptr, const int* __restrict__ e_src,
    const float* __restrict__ e_w, unsigned short* __restrict__ xagg)
{
    const int wid = threadIdx.x >> 6, lane = threadIdx.x & 63;
    const long node = (long)blockIdx.x * 4 + wid;
    if (node >= kN) return;
    const int c0 = lane << 2;

    f32x4 a = {0.f, 0.f, 0.f, 0.f};
    int b = rowptr[node];
    const int e = rowptr[node + 1];
    for (; b + 4 <= e; b += 4) {
        const int s0 = e_src[b],     s1 = e_src[b + 1];
        const int s2 = e_src[b + 2], s3 = e_src[b + 3];
        const float w0 = e_w[b],     w1 = e_w[b + 1];
        const float w2 = e_w[b + 2], w3 = e_w[b + 3];
        ushort4 v0 = *(const ushort4*)(act + (long)s0 * 256 + c0);
        ushort4 v1 = *(const ushort4*)(act + (long)s1 * 256 + c0);
        ushort4 v2 = *(const ushort4*)(act + (long)s2 * 256 + c0);
        ushort4 v3 = *(const ushort4*)(act + (long)s3 * 256 + c0);
        a[0] += w0 * bf2f(v0.x) + w1 * bf2f(v1.x) + w2 * bf2f(v2.x) + w3 * bf2f(v3.x);
        a[1] += w0 * bf2f(v0.y) + w1 * bf2f(v1.y) + w2 * bf2f(v2.y) + w3 * bf2f(v3.y);
        a[2] += w0 * bf2f(v0.z) + w1 * bf2f(v1.z) + w2 * bf2f(v2.z) + w3 * bf2f(v3.z);
        a[3] += w0 * bf2f(v0.w) + w1 * bf2f(v1.w) + w2 * bf2f(v2.w) + w3 * bf2f(v3.w);
    }
    for (; b < e; ++b) {
        const int s = e_src[b];
        const float w = e_w[b];
        ushort4 sv = *(const ushort4*)(act + (long)s * 256 + c0);
        a[0] += w * bf2f(sv.x); a[1] += w * bf2f(sv.y);
        a[2] += w * bf2f(sv.z); a[3] += w * bf2f(sv.w);
    }
    uint2 pk;
    pk.x = (unsigned)f2bf(a[0]) | ((unsigned)f2bf(a[1]) << 16);
    pk.y = (unsigned)f2bf(a[2]) | ((unsigned)f2bf(a[3]) << 16);
    *(uint2*)(xagg + node * 256 + c0) = pk;
}

// ---------------------------------------------------------------------------
// Weight conversion
// ---------------------------------------------------------------------------
__global__ __launch_bounds__(256) void cvt_w1_kernel(
    const float* __restrict__ W1, const float* __restrict__ Wl1,
    unsigned short* __restrict__ out)
{
    int idx = blockIdx.x * 256 + threadIdx.x;       // 512*1024
    if (idx >= 512 * 1024) return;
    int c = idx >> 10, k = idx & 1023;
    float v = 0.f;
    if (k < kDIN) v = (c < 256) ? W1[(long)k * 256 + c] : Wl1[(long)k * 256 + (c - 256)];
    out[idx] = f2bf(v);
}

// blkc layout: [l][out-col c][k] ; k<256 -> Wl[k][c], k>=256 -> W[k-256][c]
__global__ __launch_bounds__(256) void cvt_blk_kernel(
    const float* __restrict__ blkW, const float* __restrict__ blkWl,
    unsigned short* __restrict__ out)
{
    int idx = blockIdx.x * 256 + threadIdx.x;       // 12*256*512
    if (idx >= 12 * 256 * 512) return;
    int l = idx >> 17;
    int rem = idx & 131071;
    int c = rem >> 9, k = rem & 511;
    float v = (k < 256) ? blkWl[((long)l * 256 + k) * 256 + c]
                        : blkW[((long)l * 256 + (k - 256)) * 256 + c];
    out[idx] = f2bf(v);
}

// ---------------------------------------------------------------------------
// CSR build: histogram -> hierarchical exclusive scan -> fill
// ---------------------------------------------------------------------------
__global__ __launch_bounds__(256) void hist_kernel(const int* __restrict__ dst,
                                                   int* __restrict__ counts)
{
    int e = blockIdx.x * 256 + threadIdx.x;
    if (e < kE) atomicAdd(&counts[dst[e]], 1);
}

__global__ __launch_bounds__(1024) void scan1_kernel(
    const int* __restrict__ counts, int* __restrict__ rowptr, int* __restrict__ bsum)
{
    __shared__ int s[1024];
    const int tid = threadIdx.x;
    const int g = blockIdx.x * 1024 + tid;
    const int v = (g < kN) ? counts[g] : 0;
    s[tid] = v; __syncthreads();
    for (int off = 1; off < 1024; off <<= 1) {
        int tv = (tid >= off) ? s[tid - off] : 0;
        __syncthreads();
        s[tid] += tv;
        __syncthreads();
    }
    if (g < kN) rowptr[g] = s[tid] - v;
    if (tid == 1023) bsum[blockIdx.x] = s[1023];
}

__global__ __launch_bounds__(64) void scan2_kernel(int* __restrict__ bsum, int nb)
{
    __shared__ int s[64];
    const int tid = threadIdx.x;
    const int v = (tid < nb) ? bsum[tid] : 0;
    s[tid] = v; __syncthreads();
    for (int off = 1; off < 64; off <<= 1) {
        int tv = (tid >= off) ? s[tid - off] : 0;
        __syncthreads();
        s[tid] += tv;
        __syncthreads();
    }
    if (tid < nb) bsum[tid] = s[tid] - v;
}

__global__ __launch_bounds__(256) void scan3_kernel(
    int* __restrict__ rowptr, const int* __restrict__ bsum, int* __restrict__ cursor)
{
    int g = blockIdx.x * 256 + threadIdx.x;
    if (g < kN) {
        int r = rowptr[g] + bsum[g >> 10];
        rowptr[g] = r;
        cursor[g] = r;
    }
    if (g == 0) rowptr[kN] = kE;
}

__global__ __launch_bounds__(256) void fill_kernel(
    const int* __restrict__ src, const int* __restrict__ dst,
    const float* __restrict__ ew, int* __restrict__ cursor,
    int* __restrict__ e_src, float* __restrict__ e_w)
{
    int e = blockIdx.x * 256 + threadIdx.x;
    if (e >= kE) return;
    int d = dst[e];
    int pos = atomicAdd(&cursor[d], 1);
    e_src[pos] = src[e];
    e_w[pos] = ew[e];
}

// ---------------------------------------------------------------------------
// Final layer (DOUT=3): one wave per row, reads bf16 hidden
// ---------------------------------------------------------------------------
__global__ __launch_bounds__(64) void final_layer_kernel(
    const unsigned short* __restrict__ hbf, const float* __restrict__ W2,
    const float* __restrict__ Wl2, const float* __restrict__ b2,
    float* __restrict__ sup2, float* __restrict__ x_out)
{
    const int row = blockIdx.x;
    const int lane = threadIdx.x;
    const unsigned short* hr = hbf + (long)row * kH;
    float accW[3] = {0.f, 0.f, 0.f};
    float accL[3] = {0.f, 0.f, 0.f};
#pragma unroll
    for (int kb = 0; kb < kH / 64; ++kb) {
        int k = kb * 64 + lane;
        float v = bf2f(hr[k]);
#pragma unroll
        for (int c = 0; c < 3; ++c) {
            accW[c] = fmaf(v, W2[k * 3 + c], accW[c]);
            accL[c] = fmaf(v, Wl2[k * 3 + c], accL[c]);
        }
    }
#pragma unroll
    for (int off = 32; off > 0; off >>= 1) {
#pragma unroll
        for (int c = 0; c < 3; ++c) {
            accW[c] += __shfl_down(accW[c], off);
            accL[c] += __shfl_down(accL[c], off);
        }
    }
    if (lane == 0) {
#pragma unroll
        for (int c = 0; c < 3; ++c) {
            sup2[row * 3 + c] = accW[c];
            x_out[row * 3 + c] = accL[c] + b2[c];
        }
    }
}

__global__ __launch_bounds__(256) void scatter3_kernel(
    const float* __restrict__ sup2, const int* __restrict__ src,
    const int* __restrict__ dst, const float* __restrict__ ew,
    float* __restrict__ x_out)
{
    int e = blockIdx.x * 256 + threadIdx.x;
    if (e >= kE) return;
    int s = src[e];
    int d = dst[e];
    float w = ew[e];
#pragma unroll
    for (int c = 0; c < 3; ++c)
        atomicAdd(&x_out[(long)d * 3 + c], w * sup2[(long)s * 3 + c]);
}

// ---------------------------------------------------------------------------
extern "C" void kernel_launch(void* const* d_in, const int* in_sizes, int n_in,
                              void* d_out, int out_size, void* d_ws, size_t ws_size,
                              hipStream_t stream)
{
    const float* x    = (const float*)d_in[0];
    const int*   src  = (const int*)d_in[1];
    const int*   dst  = (const int*)d_in[2];
    const float* ew   = (const float*)d_in[3];
    const float* W1   = (const float*)d_in[4];
    const float* Wl1  = (const float*)d_in[5];
    const float* b1   = (const float*)d_in[6];
    const float* blkW  = (const float*)d_in[7];
    const float* blkWl = (const float*)d_in[8];
    const float* blkb  = (const float*)d_in[9];
    const float* W2   = (const float*)d_in[10];
    const float* Wl2  = (const float*)d_in[11];
    const float* b2   = (const float*)d_in[12];

    float* out   = (float*)d_out;
    float* x_out = out;                       // N*3
    float* h     = out + (long)kN * 3;        // N*H fp32 = x_hidden output

    // ---- workspace carve-up
    char* w = (char*)d_ws;
    size_t off = 0;
    auto carve = [&](size_t bytes) { char* p = w + off; off = (off + bytes + 255) & ~(size_t)255; return p; };
    unsigned short* supb  = (unsigned short*)carve(12800000UL * 2);
    unsigned short* tpreb = (unsigned short*)carve(12800000UL * 2);  // layer-1 only
    unsigned short* tact  = (unsigned short*)carve(12800000UL * 2);
    unsigned short* hbf   = (unsigned short*)carve(12800000UL * 2);
    unsigned short* w1c   = (unsigned short*)carve(512UL * 1024 * 2);
    unsigned short* blkc  = (unsigned short*)carve(12UL * 256 * 512 * 2);
    int*   e_src  = (int*)carve(kE * 4);
    float* e_w    = (float*)carve(kE * 4);
    int*   counts = (int*)carve(50176 * 4);
    int*   rowptr = (int*)carve(50176 * 4);
    int*   cursor = (int*)carve(50176 * 4);
    int*   bsum   = (int*)carve(64 * 4);
    float* sup2   = (float*)carve((long)kN * 3 * 4);
    unsigned short* xagg = tpreb;             // alias: tpreb dead after agg0

    // ---- CSR build
    hipMemsetAsync(counts, 0, 50176 * 4, stream);
    hist_kernel<<<(kE + 255) / 256, 256, 0, stream>>>(dst, counts);
    scan1_kernel<<<49, 1024, 0, stream>>>(counts, rowptr, bsum);
    scan2_kernel<<<1, 64, 0, stream>>>(bsum, 49);
    scan3_kernel<<<(kN + 255) / 256, 256, 0, stream>>>(rowptr, bsum, cursor);
    fill_kernel<<<(kE + 255) / 256, 256, 0, stream>>>(src, dst, ew, cursor, e_src, e_w);

    // ---- weight conversion
    cvt_w1_kernel<<<2048, 256, 0, stream>>>(W1, Wl1, w1c);
    cvt_blk_kernel<<<6144, 256, 0, stream>>>(blkW, blkWl, blkc);

    const int l1_grid  = 2 * ((kN + 127) / 128);   // 782
    const int blk_grid = 2 * ((kN + 127) / 128);   // 782 (2 col-tiles of 128)
    const int agg_grid = (kN + 3) / 4;

    // ---- Layer 1 (old order): hbf = bf16(relu(gconv(x)))
    gemm_l1<<<l1_grid, 512, 0, stream>>>(x, w1c, b1, supb, tpreb,
                                         kN, 1024, kDIN, kDIN);
    agg0_kernel<<<agg_grid, 256, 0, stream>>>(supb, tpreb, rowptr, e_src, e_w, hbf);

    // ---- 12 block convs (linearity order: agg-first, K=512 fused GEMM)
    for (int l = 0; l < 2 * kNBLK; ++l) {
        const unsigned short* act_in = (l & 1) ? tact : hbf;
        unsigned short* act_out      = (l & 1) ? hbf : tact;
        aggx_kernel<<<agg_grid, 256, 0, stream>>>(act_in, rowptr, e_src, e_w, xagg);
        const unsigned short* B = blkc + (long)l * 256 * 512;
        const float* bb = blkb + (long)l * 256;
        if (l & 1) {
            if (l == 2 * kNBLK - 1)
                gemm_blk<2><<<blk_grid, 256, 0, stream>>>(act_in, xagg, B, bb, hbf, act_out, h);
            else
                gemm_blk<1><<<blk_grid, 256, 0, stream>>>(act_in, xagg, B, bb, hbf, act_out, nullptr);
        } else {
            gemm_blk<0><<<blk_grid, 256, 0, stream>>>(act_in, xagg, B, bb, nullptr, act_out, nullptr);
        }
    }

    // ---- final layer
    final_layer_kernel<<<kN, 64, 0, stream>>>(hbf, W2, Wl2, b2, sup2, x_out);
    scatter3_kernel<<<(kE + 255) / 256, 256, 0, stream>>>(sup2, src, dst, ew, x_out);
}

// Round 11
// 961.733 us; speedup vs baseline: 7.9927x; 1.0184x over previous
//
#include <hip/hip_runtime.h>

typedef __attribute__((ext_vector_type(8))) short short8;
typedef __attribute__((ext_vector_type(4))) float f32x4;
typedef __attribute__((ext_vector_type(4), aligned(4))) float f32x4u;  // 4B-aligned loads

constexpr int kN = 50000;
constexpr int kE = 300000;
constexpr int kDIN = 963;
constexpr int kH = 256;
constexpr int kNBLK = 6;

__device__ inline unsigned short f2bf(float f) {
    unsigned u = __float_as_uint(f);
    u = u + 0x7FFFu + ((u >> 16) & 1u);   // RTNE
    return (unsigned short)(u >> 16);
}
__device__ inline float bf2f(unsigned short s) {
    return __uint_as_float(((unsigned)s) << 16);
}

__device__ inline void gload_lds16(const void* g, void* l) {
    __builtin_amdgcn_global_load_lds(
        (const __attribute__((address_space(1))) void*)g,
        (__attribute__((address_space(3))) void*)l, 16, 0, 0);
}

// ---------------------------------------------------------------------------
// Layer-1 dual GEMM: [supb | tpreb] = x @ [W1|Wl1]^T
// fp32 A converted in-kernel (vectorized chunk loads), K=963 pad 1024.
// Tile 128x256, 8 waves (2x4), grid 782 (2 col-tiles x 391), XCD swizzle.
// ---------------------------------------------------------------------------
__global__ __launch_bounds__(512) void gemm_l1(
    const float* __restrict__ Av, const unsigned short* __restrict__ Bt,
    const float* __restrict__ bias,
    unsigned short* __restrict__ supb, unsigned short* __restrict__ tpreb,
    int M, int Kpad, int Kvalid, int Astride)
{
    __shared__ __align__(16) char smem[49152];
    char* As = smem;             // 128 rows x 128 B
    char* Bs = smem + 16384;     // 256 cols x 128 B

    const int tid = threadIdx.x;
    const int wid = tid >> 6;
    const int lane = tid & 63;
    const int wr = wid >> 2, wc = wid & 3;

    const int nwg = gridDim.x;
    const int q = nwg >> 3, r = nwg & 7;
    const int xcd = blockIdx.x & 7, idx = blockIdx.x >> 3;
    const int t = (xcd < r ? xcd * (q + 1) : r * (q + 1) + (xcd - r) * q) + idx;
    const int r0 = (t >> 1) * 128;
    const int c0 = (t & 1) * 256;

    f32x4 acc[4][4];
#pragma unroll
    for (int i = 0; i < 4; ++i)
#pragma unroll
        for (int j = 0; j < 4; ++j) acc[i][j] = f32x4{0.f, 0.f, 0.f, 0.f};

    const int l_row = lane >> 3;
    const int l_c   = lane & 7;

    for (int k0 = 0; k0 < Kpad; k0 += 64) {
#pragma unroll
        for (int p = 0; p < 4; ++p) {
            int row = wid * 32 + p * 8 + l_row;
            int csw = l_c ^ (row & 7);
            const unsigned short* g = Bt + (long)(c0 + row) * Kpad + k0 + csw * 8;
            gload_lds16(g, Bs + (wid * 32 + p * 8) * 128);
        }
        {   // reg-stage fp32 A -> bf16 LDS, vectorized where fully in-bounds
            const int row = tid >> 2;
            const int kq = tid & 3;
            int grow = r0 + row; if (grow >= M) grow = M - 1;
            const float* ar = Av + (long)grow * Astride;
#pragma unroll
            for (int j = 0; j < 2; ++j) {
                int k16 = kq * 2 + j;
                int kb = k0 + k16 * 8;
                short8 v;
                if (kb + 8 <= Kvalid) {
                    f32x4u f0 = *(const f32x4u*)(ar + kb);
                    f32x4u f1 = *(const f32x4u*)(ar + kb + 4);
#pragma unroll
                    for (int ii = 0; ii < 4; ++ii) {
                        v[ii]     = (short)f2bf(f0[ii]);
                        v[ii + 4] = (short)f2bf(f1[ii]);
                    }
                } else {
#pragma unroll
                    for (int ii = 0; ii < 8; ++ii) {
                        int k = kb + ii;
                        float f = (k < Kvalid) ? ar[k] : 0.f;
                        v[ii] = (short)f2bf(f);
                    }
                }
                *(short8*)(As + row * 128 + ((k16 ^ (row & 7)) << 4)) = v;
            }
        }
        __syncthreads();
#pragma unroll
        for (int kk = 0; kk < 2; ++kk) {
            short8 af[4], bfr[4];
            const int kg = kk * 4 + (lane >> 4);
#pragma unroll
            for (int nr = 0; nr < 4; ++nr) {
                int row = wr * 64 + nr * 16 + (lane & 15);
                af[nr] = *(const short8*)(As + row * 128 + ((kg ^ (row & 7)) << 4));
            }
#pragma unroll
            for (int mc = 0; mc < 4; ++mc) {
                int row = wc * 64 + mc * 16 + (lane & 15);
                bfr[mc] = *(const short8*)(Bs + row * 128 + ((kg ^ (row & 7)) << 4));
            }
#pragma unroll
            for (int mc = 0; mc < 4; ++mc)
#pragma unroll
                for (int nr = 0; nr < 4; ++nr)
                    acc[mc][nr] = __builtin_amdgcn_mfma_f32_16x16x32_bf16(
                        bfr[mc], af[nr], acc[mc][nr], 0, 0, 0);
        }
        __syncthreads();
    }

    const bool isSup = (c0 == 0);
    unsigned short* outp = isSup ? supb : tpreb;
    float* eL = (float*)smem;
    const int wrow = wr * 16 + (lane & 15);
    const int qc = (lane >> 4) << 2;

    for (int nr = 0; nr < 4; ++nr) {
        __syncthreads();
#pragma unroll
        for (int mc = 0; mc < 4; ++mc) {
            const int col = wc * 64 + mc * 16 + qc;
            f32x4 v = acc[mc][nr];
            if (!isSup) v += *(const f32x4*)(bias + col);
            const int c16 = col >> 2;
            *(f32x4*)(eL + wrow * 256 + ((c16 ^ wrow) << 2)) = v;
        }
        __syncthreads();
        const int tr = tid >> 4, j = tid & 15;
        const int gr = r0 + (tr >> 4) * 64 + nr * 16 + (tr & 15);
        if (gr < M) {
#pragma unroll
            for (int p = 0; p < 2; ++p) {
                const int u = j + 16 * p;
                f32x4 lo = *(const f32x4*)(eL + tr * 256 + (((2 * u) ^ tr) << 2));
                f32x4 hi = *(const f32x4*)(eL + tr * 256 + (((2 * u + 1) ^ tr) << 2));
                uint4 pk;
                pk.x = (unsigned)f2bf(lo[0]) | ((unsigned)f2bf(lo[1]) << 16);
                pk.y = (unsigned)f2bf(lo[2]) | ((unsigned)f2bf(lo[3]) << 16);
                pk.z = (unsigned)f2bf(hi[0]) | ((unsigned)f2bf(hi[1]) << 16);
                pk.w = (unsigned)f2bf(hi[2]) | ((unsigned)f2bf(hi[3]) << 16);
                *(uint4*)(outp + (long)gr * 256 + u * 8) = pk;
            }
        }
    }
}

// ---------------------------------------------------------------------------
// Block-layer fused GEMM: y = [act | xagg](Mx512) @ Bt^T + bias,
// Bt = [256 out-cols][512 k] bf16 (k<256: Wl cols, k>=256: W cols).
// RES 0: out = bf16(relu(y));  RES 1: out = bf16((hbf+relu(y))*0.5)
// RES 2: as 1, plus fp32 x_hidden write.
// Tile 128x128, 4 waves (2x2), grid 782, XCD-chunked swizzle.
// ---------------------------------------------------------------------------
template<int RES>
__global__ __launch_bounds__(256) void gemm_blk(
    const unsigned short* __restrict__ act, const unsigned short* __restrict__ xagg,
    const unsigned short* __restrict__ Bt, const float* __restrict__ bias,
    const unsigned short* __restrict__ hbf_res,
    unsigned short* __restrict__ outbf, float* __restrict__ hf32)
{
    __shared__ __align__(16) char smem[32768];
    char* As = smem;             // 128 rows x 128 B
    char* Bs = smem + 16384;     // 128 out-cols x 128 B

    const int tid = threadIdx.x;
    const int wid = tid >> 6;      // 0..3
    const int lane = tid & 63;
    const int wr = wid >> 1, wc = wid & 1;

    const int nwg = gridDim.x;
    const int q = nwg >> 3, r = nwg & 7;
    const int xcd = blockIdx.x & 7, idx = blockIdx.x >> 3;
    const int t = (xcd < r ? xcd * (q + 1) : r * (q + 1) + (xcd - r) * q) + idx;
    const int r0 = (t >> 1) * 128;
    const int c0 = (t & 1) * 128;

    f32x4 acc[4][4];
#pragma unroll
    for (int i = 0; i < 4; ++i)
#pragma unroll
        for (int j = 0; j < 4; ++j) acc[i][j] = f32x4{0.f, 0.f, 0.f, 0.f};

    const int l_row = lane >> 3;
    const int l_c   = lane & 7;

    for (int k0 = 0; k0 < 512; k0 += 64) {
#pragma unroll
        for (int p = 0; p < 4; ++p) {
            int row = wid * 32 + p * 8 + l_row;
            int csw = l_c ^ (row & 7);
            const unsigned short* g = Bt + (long)(c0 + row) * 512 + k0 + csw * 8;
            gload_lds16(g, Bs + (wid * 32 + p * 8) * 128);
        }
        const unsigned short* Asrc = (k0 < 256) ? (act + k0) : (xagg + (k0 - 256));
#pragma unroll
        for (int p = 0; p < 4; ++p) {
            int row = wid * 32 + p * 8 + l_row;
            int grow = r0 + row; if (grow >= kN) grow = kN - 1;
            int csw = l_c ^ (row & 7);
            const unsigned short* g = Asrc + (long)grow * 256 + csw * 8;
            gload_lds16(g, As + (wid * 32 + p * 8) * 128);
        }
        __syncthreads();
#pragma unroll
        for (int kk = 0; kk < 2; ++kk) {
            short8 af[4], bfr[4];
            const int kg = kk * 4 + (lane >> 4);
#pragma unroll
            for (int nr = 0; nr < 4; ++nr) {
                int row = wr * 64 + nr * 16 + (lane & 15);
                af[nr] = *(const short8*)(As + row * 128 + ((kg ^ (row & 7)) << 4));
            }
#pragma unroll
            for (int mc = 0; mc < 4; ++mc) {
                int row = wc * 64 + mc * 16 + (lane & 15);
                bfr[mc] = *(const short8*)(Bs + row * 128 + ((kg ^ (row & 7)) << 4));
            }
#pragma unroll
            for (int mc = 0; mc < 4; ++mc)
#pragma unroll
                for (int nr = 0; nr < 4; ++nr)
                    acc[mc][nr] = __builtin_amdgcn_mfma_f32_16x16x32_bf16(
                        bfr[mc], af[nr], acc[mc][nr], 0, 0, 0);
        }
        __syncthreads();
    }

    float* eL = (float*)smem;                 // 32 x 128 fp32 = 16 KB
    const int wrow = wr * 16 + (lane & 15);   // 0..31
    const int qc = (lane >> 4) << 2;

    for (int nr = 0; nr < 4; ++nr) {
        __syncthreads();
#pragma unroll
        for (int mc = 0; mc < 4; ++mc) {
            const int col = wc * 64 + mc * 16 + qc;   // 0..127
            f32x4 v = acc[mc][nr] + *(const f32x4*)(bias + c0 + col);
            const int c16 = col >> 2;                 // 0..31
            *(f32x4*)(eL + wrow * 128 + ((c16 ^ wrow) << 2)) = v;
        }
        __syncthreads();
        const int tr = tid >> 3, j = tid & 7;         // 32 rows x 8 threads
        const int gr = r0 + (tr >> 4) * 64 + nr * 16 + (tr & 15);
        if (gr < kN) {
#pragma unroll
            for (int p = 0; p < 2; ++p) {
                const int u = j + 8 * p;              // 16B bf16 unit, 0..15
                f32x4 lo = *(const f32x4*)(eL + tr * 128 + (((2 * u) ^ tr) << 2));
                f32x4 hi = *(const f32x4*)(eL + tr * 128 + (((2 * u + 1) ^ tr) << 2));
#pragma unroll
                for (int ii = 0; ii < 4; ++ii) {
                    lo[ii] = fmaxf(lo[ii], 0.f);
                    hi[ii] = fmaxf(hi[ii], 0.f);
                }
                const long gcol = (long)gr * 256 + c0 + u * 8;
                if (RES >= 1) {
                    uint4 hv = *(const uint4*)(hbf_res + gcol);
                    lo[0] = (bf2f((unsigned short)(hv.x & 0xFFFF)) + lo[0]) * 0.5f;
                    lo[1] = (bf2f((unsigned short)(hv.x >> 16))    + lo[1]) * 0.5f;
                    lo[2] = (bf2f((unsigned short)(hv.y & 0xFFFF)) + lo[2]) * 0.5f;
                    lo[3] = (bf2f((unsigned short)(hv.y >> 16))    + lo[3]) * 0.5f;
                    hi[0] = (bf2f((unsigned short)(hv.z & 0xFFFF)) + hi[0]) * 0.5f;
                    hi[1] = (bf2f((unsigned short)(hv.z >> 16))    + hi[1]) * 0.5f;
                    hi[2] = (bf2f((unsigned short)(hv.w & 0xFFFF)) + hi[2]) * 0.5f;
                    hi[3] = (bf2f((unsigned short)(hv.w >> 16))    + hi[3]) * 0.5f;
                }
                if (RES == 2) {
                    *(f32x4*)(hf32 + gcol)     = lo;
                    *(f32x4*)(hf32 + gcol + 4) = hi;
                }
                uint4 pk;
                pk.x = (unsigned)f2bf(lo[0]) | ((unsigned)f2bf(lo[1]) << 16);
                pk.y = (unsigned)f2bf(lo[2]) | ((unsigned)f2bf(lo[3]) << 16);
                pk.z = (unsigned)f2bf(hi[0]) | ((unsigned)f2bf(hi[1]) << 16);
                pk.w = (unsigned)f2bf(hi[2]) | ((unsigned)f2bf(hi[3]) << 16);
                *(uint4*)(outbf + gcol) = pk;
            }
        }
    }
}

// ---------------------------------------------------------------------------
// 16B-lane CSR gather. One 32-lane half-wave per node; lane owns 8 bf16 cols
// (uint4 loads). 4-edge unroll -> 64 B/lane in flight.
// MODE 0: xagg = bf16(sum ew*act[src])
// MODE 1: hbf  = bf16(relu(tpreb + sum ew*supb[src]))   (layer 1)
// ---------------------------------------------------------------------------
template<int MODE>
__global__ __launch_bounds__(256) void agg16_kernel(
    const unsigned short* __restrict__ srcbuf, const unsigned short* __restrict__ tpreb,
    const int* __restrict__ rowptr, const int* __restrict__ e_src,
    const float* __restrict__ e_w, unsigned short* __restrict__ outb)
{
    const int tid = threadIdx.x;
    const int sub = tid >> 5;          // 0..7 half-wave in block
    const int l   = tid & 31;
    const long node = (long)blockIdx.x * 8 + sub;
    if (node >= kN) return;
    const int c0 = l * 8;              // 8 cols = 16 B

    f32x4 a0 = {0.f, 0.f, 0.f, 0.f}, a1 = {0.f, 0.f, 0.f, 0.f};
    if (MODE == 1) {
        uint4 tv = *(const uint4*)(tpreb + node * 256 + c0);
        a0[0] = bf2f((unsigned short)(tv.x & 0xFFFF)); a0[1] = bf2f((unsigned short)(tv.x >> 16));
        a0[2] = bf2f((unsigned short)(tv.y & 0xFFFF)); a0[3] = bf2f((unsigned short)(tv.y >> 16));
        a1[0] = bf2f((unsigned short)(tv.z & 0xFFFF)); a1[1] = bf2f((unsigned short)(tv.z >> 16));
        a1[2] = bf2f((unsigned short)(tv.w & 0xFFFF)); a1[3] = bf2f((unsigned short)(tv.w >> 16));
    }

    int b = rowptr[node];
    const int e = rowptr[node + 1];

#define ACC16(V, W) \
    a0[0] += (W) * bf2f((unsigned short)((V).x & 0xFFFF)); \
    a0[1] += (W) * bf2f((unsigned short)((V).x >> 16));    \
    a0[2] += (W) * bf2f((unsigned short)((V).y & 0xFFFF)); \
    a0[3] += (W) * bf2f((unsigned short)((V).y >> 16));    \
    a1[0] += (W) * bf2f((unsigned short)((V).z & 0xFFFF)); \
    a1[1] += (W) * bf2f((unsigned short)((V).z >> 16));    \
    a1[2] += (W) * bf2f((unsigned short)((V).w & 0xFFFF)); \
    a1[3] += (W) * bf2f((unsigned short)((V).w >> 16));

    for (; b + 4 <= e; b += 4) {
        const int s0 = e_src[b],     s1 = e_src[b + 1];
        const int s2 = e_src[b + 2], s3 = e_src[b + 3];
        const float w0 = e_w[b],     w1 = e_w[b + 1];
        const float w2 = e_w[b + 2], w3 = e_w[b + 3];
        uint4 v0 = *(const uint4*)(srcbuf + (long)s0 * 256 + c0);
        uint4 v1 = *(const uint4*)(srcbuf + (long)s1 * 256 + c0);
        uint4 v2 = *(const uint4*)(srcbuf + (long)s2 * 256 + c0);
        uint4 v3 = *(const uint4*)(srcbuf + (long)s3 * 256 + c0);
        ACC16(v0, w0) ACC16(v1, w1) ACC16(v2, w2) ACC16(v3, w3)
    }
    for (; b < e; ++b) {
        const int s = e_src[b];
        const float w = e_w[b];
        uint4 v = *(const uint4*)(srcbuf + (long)s * 256 + c0);
        ACC16(v, w)
    }
#undef ACC16

    if (MODE == 1) {
#pragma unroll
        for (int ii = 0; ii < 4; ++ii) {
            a0[ii] = fmaxf(a0[ii], 0.f);
            a1[ii] = fmaxf(a1[ii], 0.f);
        }
    }
    uint4 pk;
    pk.x = (unsigned)f2bf(a0[0]) | ((unsigned)f2bf(a0[1]) << 16);
    pk.y = (unsigned)f2bf(a0[2]) | ((unsigned)f2bf(a0[3]) << 16);
    pk.z = (unsigned)f2bf(a1[0]) | ((unsigned)f2bf(a1[1]) << 16);
    pk.w = (unsigned)f2bf(a1[2]) | ((unsigned)f2bf(a1[3]) << 16);
    *(uint4*)(outb + node * 256 + c0) = pk;
}

// ---------------------------------------------------------------------------
// Weight conversion
// ---------------------------------------------------------------------------
__global__ __launch_bounds__(256) void cvt_w1_kernel(
    const float* __restrict__ W1, const float* __restrict__ Wl1,
    unsigned short* __restrict__ out)
{
    int idx = blockIdx.x * 256 + threadIdx.x;       // 512*1024
    if (idx >= 512 * 1024) return;
    int c = idx >> 10, k = idx & 1023;
    float v = 0.f;
    if (k < kDIN) v = (c < 256) ? W1[(long)k * 256 + c] : Wl1[(long)k * 256 + (c - 256)];
    out[idx] = f2bf(v);
}

// blkc layout: [l][out-col c][k] ; k<256 -> Wl[k][c], k>=256 -> W[k-256][c]
__global__ __launch_bounds__(256) void cvt_blk_kernel(
    const float* __restrict__ blkW, const float* __restrict__ blkWl,
    unsigned short* __restrict__ out)
{
    int idx = blockIdx.x * 256 + threadIdx.x;       // 12*256*512
    if (idx >= 12 * 256 * 512) return;
    int l = idx >> 17;
    int rem = idx & 131071;
    int c = rem >> 9, k = rem & 511;
    float v = (k < 256) ? blkWl[((long)l * 256 + k) * 256 + c]
                        : blkW[((long)l * 256 + (k - 256)) * 256 + c];
    out[idx] = f2bf(v);
}

// ---------------------------------------------------------------------------
// CSR build: histogram -> hierarchical exclusive scan -> fill
// ---------------------------------------------------------------------------
__global__ __launch_bounds__(256) void hist_kernel(const int* __restrict__ dst,
                                                   int* __restrict__ counts)
{
    int e = blockIdx.x * 256 + threadIdx.x;
    if (e < kE) atomicAdd(&counts[dst[e]], 1);
}

__global__ __launch_bounds__(1024) void scan1_kernel(
    const int* __restrict__ counts, int* __restrict__ rowptr, int* __restrict__ bsum)
{
    __shared__ int s[1024];
    const int tid = threadIdx.x;
    const int g = blockIdx.x * 1024 + tid;
    const int v = (g < kN) ? counts[g] : 0;
    s[tid] = v; __syncthreads();
    for (int off = 1; off < 1024; off <<= 1) {
        int tv = (tid >= off) ? s[tid - off] : 0;
        __syncthreads();
        s[tid] += tv;
        __syncthreads();
    }
    if (g < kN) rowptr[g] = s[tid] - v;
    if (tid == 1023) bsum[blockIdx.x] = s[1023];
}

__global__ __launch_bounds__(64) void scan2_kernel(int* __restrict__ bsum, int nb)
{
    __shared__ int s[64];
    const int tid = threadIdx.x;
    const int v = (tid < nb) ? bsum[tid] : 0;
    s[tid] = v; __syncthreads();
    for (int off = 1; off < 64; off <<= 1) {
        int tv = (tid >= off) ? s[tid - off] : 0;
        __syncthreads();
        s[tid] += tv;
        __syncthreads();
    }
    if (tid < nb) bsum[tid] = s[tid] - v;
}

__global__ __launch_bounds__(256) void scan3_kernel(
    int* __restrict__ rowptr, const int* __restrict__ bsum, int* __restrict__ cursor)
{
    int g = blockIdx.x * 256 + threadIdx.x;
    if (g < kN) {
        int r = rowptr[g] + bsum[g >> 10];
        rowptr[g] = r;
        cursor[g] = r;
    }
    if (g == 0) rowptr[kN] = kE;
}

__global__ __launch_bounds__(256) void fill_kernel(
    const int* __restrict__ src, const int* __restrict__ dst,
    const float* __restrict__ ew, int* __restrict__ cursor,
    int* __restrict__ e_src, float* __restrict__ e_w)
{
    int e = blockIdx.x * 256 + threadIdx.x;
    if (e >= kE) return;
    int d = dst[e];
    int pos = atomicAdd(&cursor[d], 1);
    e_src[pos] = src[e];
    e_w[pos] = ew[e];
}

// ---------------------------------------------------------------------------
// Final layer (DOUT=3): one wave per row, reads bf16 hidden
// ---------------------------------------------------------------------------
__global__ __launch_bounds__(64) void final_layer_kernel(
    const unsigned short* __restrict__ hbf, const float* __restrict__ W2,
    const float* __restrict__ Wl2, const float* __restrict__ b2,
    float* __restrict__ sup2, float* __restrict__ x_out)
{
    const int row = blockIdx.x;
    const int lane = threadIdx.x;
    const unsigned short* hr = hbf + (long)row * kH;
    float accW[3] = {0.f, 0.f, 0.f};
    float accL[3] = {0.f, 0.f, 0.f};
#pragma unroll
    for (int kb = 0; kb < kH / 64; ++kb) {
        int k = kb * 64 + lane;
        float v = bf2f(hr[k]);
#pragma unroll
        for (int c = 0; c < 3; ++c) {
            accW[c] = fmaf(v, W2[k * 3 + c], accW[c]);
            accL[c] = fmaf(v, Wl2[k * 3 + c], accL[c]);
        }
    }
#pragma unroll
    for (int off = 32; off > 0; off >>= 1) {
#pragma unroll
        for (int c = 0; c < 3; ++c) {
            accW[c] += __shfl_down(accW[c], off);
            accL[c] += __shfl_down(accL[c], off);
        }
    }
    if (lane == 0) {
#pragma unroll
        for (int c = 0; c < 3; ++c) {
            sup2[row * 3 + c] = accW[c];
            x_out[row * 3 + c] = accL[c] + b2[c];
        }
    }
}

__global__ __launch_bounds__(256) void scatter3_kernel(
    const float* __restrict__ sup2, const int* __restrict__ src,
    const int* __restrict__ dst, const float* __restrict__ ew,
    float* __restrict__ x_out)
{
    int e = blockIdx.x * 256 + threadIdx.x;
    if (e >= kE) return;
    int s = src[e];
    int d = dst[e];
    float w = ew[e];
#pragma unroll
    for (int c = 0; c < 3; ++c)
        atomicAdd(&x_out[(long)d * 3 + c], w * sup2[(long)s * 3 + c]);
}

// ---------------------------------------------------------------------------
extern "C" void kernel_launch(void* const* d_in, const int* in_sizes, int n_in,
                              void* d_out, int out_size, void* d_ws, size_t ws_size,
                              hipStream_t stream)
{
    const float* x    = (const float*)d_in[0];
    const int*   src  = (const int*)d_in[1];
    const int*   dst  = (const int*)d_in[2];
    const float* ew   = (const float*)d_in[3];
    const float* W1   = (const float*)d_in[4];
    const float* Wl1  = (const float*)d_in[5];
    const float* b1   = (const float*)d_in[6];
    const float* blkW  = (const float*)d_in[7];
    const float* blkWl = (const float*)d_in[8];
    const float* blkb  = (const float*)d_in[9];
    const float* W2   = (const float*)d_in[10];
    const float* Wl2  = (const float*)d_in[11];
    const float* b2   = (const float*)d_in[12];

    float* out   = (float*)d_out;
    float* x_out = out;                       // N*3
    float* h     = out + (long)kN * 3;        // N*H fp32 = x_hidden output

    // ---- workspace carve-up
    char* w = (char*)d_ws;
    size_t off = 0;
    auto carve = [&](size_t bytes) { char* p = w + off; off = (off + bytes + 255) & ~(size_t)255; return p; };
    unsigned short* supb  = (unsigned short*)carve(12800000UL * 2);
    unsigned short* tpreb = (unsigned short*)carve(12800000UL * 2);  // layer-1 only
    unsigned short* tact  = (unsigned short*)carve(12800000UL * 2);
    unsigned short* hbf   = (unsigned short*)carve(12800000UL * 2);
    unsigned short* w1c   = (unsigned short*)carve(512UL * 1024 * 2);
    unsigned short* blkc  = (unsigned short*)carve(12UL * 256 * 512 * 2);
    int*   e_src  = (int*)carve(kE * 4);
    float* e_w    = (float*)carve(kE * 4);
    int*   counts = (int*)carve(50176 * 4);
    int*   rowptr = (int*)carve(50176 * 4);
    int*   cursor = (int*)carve(50176 * 4);
    int*   bsum   = (int*)carve(64 * 4);
    float* sup2   = (float*)carve((long)kN * 3 * 4);
    unsigned short* xagg = tpreb;             // alias: tpreb dead after agg0

    // ---- CSR build
    hipMemsetAsync(counts, 0, 50176 * 4, stream);
    hist_kernel<<<(kE + 255) / 256, 256, 0, stream>>>(dst, counts);
    scan1_kernel<<<49, 1024, 0, stream>>>(counts, rowptr, bsum);
    scan2_kernel<<<1, 64, 0, stream>>>(bsum, 49);
    scan3_kernel<<<(kN + 255) / 256, 256, 0, stream>>>(rowptr, bsum, cursor);
    fill_kernel<<<(kE + 255) / 256, 256, 0, stream>>>(src, dst, ew, cursor, e_src, e_w);

    // ---- weight conversion
    cvt_w1_kernel<<<2048, 256, 0, stream>>>(W1, Wl1, w1c);
    cvt_blk_kernel<<<6144, 256, 0, stream>>>(blkW, blkWl, blkc);

    const int l1_grid  = 2 * ((kN + 127) / 128);   // 782
    const int blk_grid = 2 * ((kN + 127) / 128);   // 782 (2 col-tiles of 128)
    const int agg_grid = (kN + 7) / 8;             // 6250 (8 nodes/block)

    // ---- Layer 1 (old order): hbf = bf16(relu(gconv(x)))
    gemm_l1<<<l1_grid, 512, 0, stream>>>(x, w1c, b1, supb, tpreb,
                                         kN, 1024, kDIN, kDIN);
    agg16_kernel<1><<<agg_grid, 256, 0, stream>>>(supb, tpreb, rowptr, e_src, e_w, hbf);

    // ---- 12 block convs (linearity order: agg-first, K=512 fused GEMM)
    for (int l = 0; l < 2 * kNBLK; ++l) {
        const unsigned short* act_in = (l & 1) ? tact : hbf;
        unsigned short* act_out      = (l & 1) ? hbf : tact;
        agg16_kernel<0><<<agg_grid, 256, 0, stream>>>(act_in, nullptr, rowptr, e_src, e_w, xagg);
        const unsigned short* B = blkc + (long)l * 256 * 512;
        const float* bb = blkb + (long)l * 256;
        if (l & 1) {
            if (l == 2 * kNBLK - 1)
                gemm_blk<2><<<blk_grid, 256, 0, stream>>>(act_in, xagg, B, bb, hbf, act_out, h);
            else
                gemm_blk<1><<<blk_grid, 256, 0, stream>>>(act_in, xagg, B, bb, hbf, act_out, nullptr);
        } else {
            gemm_blk<0><<<blk_grid, 256, 0, stream>>>(act_in, xagg, B, bb, nullptr, act_out, nullptr);
        }
    }

    // ---- final layer
    final_layer_kernel<<<kN, 64, 0, stream>>>(hbf, W2, Wl2, b2, sup2, x_out);
    scatter3_kernel<<<(kE + 255) / 256, 256, 0, stream>>>(sup2, src, dst, ew, x_out);
}